// Round 5
// baseline (5082.931 us; speedup 1.0000x reference)
//
#include <hip/hip_runtime.h>
#include <hip/hip_bf16.h>

#define N_NODES 4096
#define T_STEPS 8
#define INDIM   64
#define HDIM    128
#define G4      512                    // 4*H
#define NROWS   (N_NODES * T_STEPS)    // 32768

typedef __hip_bfloat16 bf16;
typedef __attribute__((ext_vector_type(8))) short bf16x8;
typedef __attribute__((ext_vector_type(4))) float f32x4;

__device__ __forceinline__ float sigm(float x) { return 1.0f / (1.0f + __expf(-x)); }
__device__ __forceinline__ float tanh_(float x) {
    x = fminf(fmaxf(x, -15.f), 15.f);
    float e = __expf(2.f * x);
    return (e - 1.f) / (e + 1.f);
}
__device__ __forceinline__ float bfbits2f(unsigned int u) {
    union { unsigned int i; float f; } v; v.i = u << 16; return v.f;
}
__device__ __forceinline__ unsigned int f2bfbits(float f) {
    bf16 b = __float2bfloat16(f);
    unsigned short u; __builtin_memcpy(&u, &b, 2); return (unsigned int)u;
}

// ---------------- K0: fold weights + bf16 conversions ------------------------
#define P_O0 32768
#define P_O1 (P_O0 + 512)
#define P_O2 (P_O1 + 16384)
#define P_O3 (P_O2 + 16384)
#define P_O4 (P_O3 + 128)
#define P_O5 (P_O4 + 1)
#define P_O6 (P_O5 + 65536)
__global__ void prep_kernel(const float* __restrict__ pre_w, const float* __restrict__ pre_b,
                            const float* __restrict__ w_ih, const float* __restrict__ b_ih,
                            const float* __restrict__ b_hh, const float* __restrict__ w_hh,
                            const float* __restrict__ wsrc, const float* __restrict__ wdst,
                            const float* __restrict__ out_w, const float* __restrict__ out_b,
                            const float* __restrict__ gat_b,
                            float* __restrict__ Wc, float* __restrict__ bc,
                            float* __restrict__ wsT, float* __restrict__ wdT,
                            float* __restrict__ wso, float* __restrict__ cy,
                            bf16* __restrict__ whhb) {
    int id = blockIdx.x * 256 + threadIdx.x;
    if (id < P_O0) {
        int g = id >> 6, i = id & 63;
        float s = 0.f;
        for (int k = 0; k < HDIM; k++) s += pre_w[i * HDIM + k] * w_ih[g * HDIM + k];
        Wc[id] = s;
    } else if (id < P_O1) {
        int g = id - P_O0;
        float s = b_ih[g] + b_hh[g];
        for (int k = 0; k < HDIM; k++) s += pre_b[k] * w_ih[g * HDIM + k];
        bc[g] = s;
    } else if (id < P_O2) {
        int c = id - P_O1;
        int co = c >> 7, k = c & 127;
        wsT[c] = wsrc[k * HDIM + co];
    } else if (id < P_O3) {
        int c = id - P_O2;
        int co = c >> 7, k = c & 127;
        wdT[c] = wdst[k * HDIM + co];
    } else if (id < P_O4) {
        int hi = id - P_O3;
        float s = 0.f;
        for (int ho = 0; ho < HDIM; ho++) s += wsrc[hi * HDIM + ho] * out_w[ho];
        wso[hi] = s;
    } else if (id == P_O4) {
        float s = out_b[0];
        for (int h = 0; h < HDIM; h++) s += gat_b[h] * out_w[h];
        cy[0] = s;
    } else if (id < P_O6) {
        int c = id - P_O5;
        whhb[c] = __float2bfloat16(w_hh[c]);
    }
}

// ---------------- K1: xw[row][h*4+gate] = input[row,:64] . Wc[g,:] + bc[g] ---
// NOTE layout: gate-interleaved per h so the LSTM lane reads one dwordx4.
__global__ __launch_bounds__(512) void xw_kernel(const float* __restrict__ input,
                                                 const float* __restrict__ Wc,
                                                 const float* __restrict__ bc,
                                                 bf16* __restrict__ xw) {
    __shared__ __align__(16) float in_lds[16 * INDIM];   // 4KB: 16 rows
    int tid = threadIdx.x;
    int rowbase = blockIdx.x * 16;
    in_lds[tid]       = input[(size_t)rowbase * INDIM + tid];
    in_lds[tid + 512] = input[(size_t)rowbase * INDIM + tid + 512];
    __syncthreads();
    int g = tid;
    int gate = g >> 7, hh = g & 127;
    float4 w[16];
    const float4* wr = reinterpret_cast<const float4*>(Wc + g * INDIM);
#pragma unroll
    for (int u = 0; u < 16; u++) w[u] = wr[u];
    float b = bc[g];
    for (int r = 0; r < 16; r++) {
        const float4* hv = reinterpret_cast<const float4*>(in_lds + r * INDIM);
        float a0 = b, a1 = 0.f, a2 = 0.f, a3 = 0.f;
#pragma unroll
        for (int u = 0; u < 16; u++) {
            float4 h4 = hv[u]; float4 wv = w[u];
            a0 = fmaf(h4.x, wv.x, a0); a1 = fmaf(h4.y, wv.y, a1);
            a2 = fmaf(h4.z, wv.z, a2); a3 = fmaf(h4.w, wv.w, a3);
        }
        xw[(size_t)(rowbase + r) * G4 + hh * 4 + gate] = __float2bfloat16((a0 + a1) + (a2 + a3));
    }
}

// ---------------- K2: sequential LSTM scan, all 8 chains batched -------------
// 1 block, 512 threads (8 waves). B = [h^0 .. h^7] fills 8 MFMA columns.
// Wave w owns gate tiles {w, 8+w, 16+w, 24+w} => lane holds i,f,g,o of the
// SAME h in-register -> gate math in-lane, no g_lds, 1 barrier/step (dbuf h).
__global__ __launch_bounds__(512, 1) void lstm_kernel(const bf16* __restrict__ xw,
                                                      const bf16* __restrict__ whhb,
                                                      const float* __restrict__ hidden0,
                                                      const float* __restrict__ cell0,
                                                      float* __restrict__ outs,
                                                      float* __restrict__ dout) {
    __shared__ __align__(16) char hbuf0[2048];   // h matrix [t][k] bf16, XOR-swizzled
    __shared__ __align__(16) char hbuf1[2048];
    const int tid  = threadIdx.x;
    const int w    = tid >> 6;
    const int lane = tid & 63;
    const int kg   = lane >> 4;        // 0..3
    const int lr   = lane & 15;
    const int t    = lr & 7;           // chain (MFMA column)
    const int rp   = lr >> 3;          // row-pair select within C regs
    const int hb   = 16 * w + kg * 4 + 2 * rp;   // first of this lane's 2 h indices

    // Persistent A fragments: gate G tile rows G*128+16w .. +16, all 4 K-tiles
    bf16x8 afr[4][4];
#pragma unroll
    for (int G = 0; G < 4; G++) {
        const unsigned short* rowp =
            reinterpret_cast<const unsigned short*>(whhb) + (size_t)(G * 128 + 16 * w + lr) * HDIM;
#pragma unroll
        for (int kt = 0; kt < 4; kt++)
            afr[G][kt] = *reinterpret_cast<const bf16x8*>(rowp + kt * 32 + kg * 8);
    }

    // swizzled LDS offsets (read: row t, bytes kt*64+kg*16; write: byte hb*2)
    const int boff0 = t * 256 + (((0 << 6) | (kg << 4)) ^ (t << 4));
    const int boff1 = t * 256 + (((1 << 6) | (kg << 4)) ^ (t << 4));
    const int boff2 = t * 256 + (((2 << 6) | (kg << 4)) ^ (t << 4));
    const int boff3 = t * 256 + (((3 << 6) | (kg << 4)) ^ (t << 4));
    const int woff  = t * 256 + ((hb * 2) ^ (t << 4));

    // init states
    float c0 = cell0[t * HDIM + hb];
    float c1 = cell0[t * HDIM + hb + 1];
    float h0v = hidden0[t * HDIM + hb];
    float h1v = hidden0[t * HDIM + hb + 1];
    *reinterpret_cast<unsigned int*>(hbuf0 + woff) = (f2bfbits(h1v) << 16) | f2bfbits(h0v);

    // xw pointer: row (n*8+t), bytes (h*4+gate)*2 -> t*1024 + hb*8 (+ n*8192)
    const uint4* xptr = reinterpret_cast<const uint4*>(
        reinterpret_cast<const char*>(xw) + (size_t)t * 1024 + (size_t)hb * 8);
    float* outp = outs + (size_t)t * HDIM + hb;

    uint4 xa = xptr[0];
    uint4 xb = xptr[512];
    __syncthreads();

#define STEPX(NIDX, RB, WB, XQ)                                                      \
    do {                                                                             \
        bf16x8 bfr0 = *reinterpret_cast<const bf16x8*>(RB + boff0);                  \
        bf16x8 bfr1 = *reinterpret_cast<const bf16x8*>(RB + boff1);                  \
        bf16x8 bfr2 = *reinterpret_cast<const bf16x8*>(RB + boff2);                  \
        bf16x8 bfr3 = *reinterpret_cast<const bf16x8*>(RB + boff3);                  \
        f32x4 acc[4];                                                                \
        _Pragma("unroll")                                                            \
        for (int G = 0; G < 4; G++) {                                                \
            f32x4 a = {0.f, 0.f, 0.f, 0.f};                                          \
            a = __builtin_amdgcn_mfma_f32_16x16x32_bf16(afr[G][0], bfr0, a, 0, 0, 0);\
            a = __builtin_amdgcn_mfma_f32_16x16x32_bf16(afr[G][1], bfr1, a, 0, 0, 0);\
            a = __builtin_amdgcn_mfma_f32_16x16x32_bf16(afr[G][2], bfr2, a, 0, 0, 0);\
            a = __builtin_amdgcn_mfma_f32_16x16x32_bf16(afr[G][3], bfr3, a, 0, 0, 0);\
            acc[G] = a;                                                              \
        }                                                                            \
        float gi0 = (rp ? acc[0][2] : acc[0][0]) + bfbits2f((XQ).x & 0xffffu);       \
        float gf0 = (rp ? acc[1][2] : acc[1][0]) + bfbits2f((XQ).x >> 16);           \
        float gg0 = (rp ? acc[2][2] : acc[2][0]) + bfbits2f((XQ).y & 0xffffu);       \
        float go0 = (rp ? acc[3][2] : acc[3][0]) + bfbits2f((XQ).y >> 16);           \
        float gi1 = (rp ? acc[0][3] : acc[0][1]) + bfbits2f((XQ).z & 0xffffu);       \
        float gf1 = (rp ? acc[1][3] : acc[1][1]) + bfbits2f((XQ).z >> 16);           \
        float gg1 = (rp ? acc[2][3] : acc[2][1]) + bfbits2f((XQ).w & 0xffffu);       \
        float go1 = (rp ? acc[3][3] : acc[3][1]) + bfbits2f((XQ).w >> 16);           \
        c0 = sigm(gf0) * c0 + sigm(gi0) * tanh_(gg0);                                \
        h0v = sigm(go0) * tanh_(c0);                                                 \
        c1 = sigm(gf1) * c1 + sigm(gi1) * tanh_(gg1);                                \
        h1v = sigm(go1) * tanh_(c1);                                                 \
        *reinterpret_cast<unsigned int*>(WB + woff) =                                \
            (f2bfbits(h1v) << 16) | f2bfbits(h0v);                                   \
        float2 o2; o2.x = h0v; o2.y = h1v;                                           \
        *reinterpret_cast<float2*>(outp + (size_t)(NIDX) * 1024) = o2;               \
        __syncthreads();                                                             \
    } while (0)

    for (int n = 0; n < N_NODES; n += 2) {
        uint4 xc = {0, 0, 0, 0}, xd = {0, 0, 0, 0};
        if (n + 2 < N_NODES) {
            xc = xptr[(size_t)(n + 2) * 512];
            xd = xptr[(size_t)(n + 3) * 512];
        }
        STEPX(n,     hbuf0, hbuf1, xa);
        STEPX(n + 1, hbuf1, hbuf0, xb);
        xa = xc; xb = xd;
    }
#undef STEPX

    float2 hv; hv.x = h0v; hv.y = h1v;
    float2 cv; cv.x = c0;  cv.y = c1;
    *reinterpret_cast<float2*>(dout + NROWS + t * HDIM + hb) = hv;
    *reinterpret_cast<float2*>(dout + NROWS + T_STEPS * HDIM + t * HDIM + hb) = cv;
}

// ---------------- K3: fs = outs@wsrc, fd = outs@wdst (bf16 out) --------------
__global__ __launch_bounds__(256) void fsfd_kernel(const float* __restrict__ outs,
                                                   const float* __restrict__ wsT,
                                                   const float* __restrict__ wdT,
                                                   bf16* __restrict__ fs,
                                                   bf16* __restrict__ fd) {
    __shared__ __align__(16) float rows[32 * HDIM];    // 16KB: 32 rows
    int tid = threadIdx.x;
    size_t base = (size_t)blockIdx.x * 32 * HDIM;
#pragma unroll
    for (int j = 0; j < 16; j++) rows[tid + j * 256] = outs[base + tid + j * 256];
    __syncthreads();
    int c = tid;
    const float4* wT = reinterpret_cast<const float4*>(
        (c < HDIM) ? (wsT + c * HDIM) : (wdT + (c - HDIM) * HDIM));
    float4 w[32];
#pragma unroll
    for (int u = 0; u < 32; u++) w[u] = wT[u];
    bf16* dst = (c < HDIM) ? (fs + base + c) : (fd + base + (c - HDIM));
    for (int r = 0; r < 32; r++) {
        const float4* hv = reinterpret_cast<const float4*>(rows + r * HDIM);
        float a0 = 0.f, a1 = 0.f, a2 = 0.f, a3 = 0.f;
#pragma unroll
        for (int u = 0; u < 32; u++) {
            float4 h4 = hv[u]; float4 wv = w[u];
            a0 = fmaf(h4.x, wv.x, a0); a1 = fmaf(h4.y, wv.y, a1);
            a2 = fmaf(h4.z, wv.z, a2); a3 = fmaf(h4.w, wv.w, a3);
        }
        dst[(size_t)r * HDIM] = __float2bfloat16((a0 + a1) + (a2 + a3));
    }
}

// ---------------- K3b: fso[row] = outs[row,:] . wso --------------------------
__global__ __launch_bounds__(256) void fso_kernel(const float* __restrict__ outs,
                                                  const float* __restrict__ wso,
                                                  float* __restrict__ fso) {
    int tid = threadIdx.x;
    int l = tid & 63;
    int row = blockIdx.x * 4 + (tid >> 6);
    float v = outs[(size_t)row * HDIM + l] * wso[l]
            + outs[(size_t)row * HDIM + 64 + l] * wso[64 + l];
#pragma unroll
    for (int m = 32; m >= 1; m >>= 1) v += __shfl_xor(v, m, 64);
    if (l == 0) fso[row] = v;
}

// ---------------- K4: per-edge softmax numerators ----------------------------
__global__ __launch_bounds__(256) void edge_kernel(const int* __restrict__ esrc,
                                                   const int* __restrict__ edst,
                                                   const bf16* __restrict__ fs,
                                                   const bf16* __restrict__ fd,
                                                   const float* __restrict__ attn,
                                                   const float* __restrict__ fso,
                                                   float* __restrict__ denom,
                                                   float* __restrict__ ynum, int nE) {
    int tid = threadIdx.x;
    int l = tid & 63;
    int e = blockIdx.x * 4 + (tid >> 6);
    if (e >= nE) return;
    int s = esrc[e], d = edst[e];
    float at1 = attn[l], at2 = attn[64 + l];
    const bf16* fsr = fs + (size_t)s * (T_STEPS * HDIM);
    const bf16* fdr = fd + (size_t)d * (T_STEPS * HDIM);
#pragma unroll
    for (int t = 0; t < T_STEPS; t++) {
        float x1 = __bfloat162float(fsr[t * HDIM + l]) + __bfloat162float(fdr[t * HDIM + l]);
        float x2 = __bfloat162float(fsr[t * HDIM + 64 + l]) + __bfloat162float(fdr[t * HDIM + 64 + l]);
        x1 = fmaxf(x1, 0.f) + 0.2f * fminf(x1, 0.f);
        x2 = fmaxf(x2, 0.f) + 0.2f * fminf(x2, 0.f);
        float v = x1 * at1 + x2 * at2;
#pragma unroll
        for (int m = 32; m >= 1; m >>= 1) v += __shfl_xor(v, m, 64);
        if (l == 0) {
            float a = __expf(v);
            atomicAdd(&denom[d * T_STEPS + t], a);
            atomicAdd(&ynum[d * T_STEPS + t], a * fso[s * T_STEPS + t]);
        }
    }
}

// ---------------- K5: finalize y ---------------------------------------------
__global__ void final_kernel(const float* __restrict__ ynum, const float* __restrict__ denom,
                             const float* __restrict__ cy, float* __restrict__ dout) {
    int i = blockIdx.x * 256 + threadIdx.x;
    if (i < NROWS) dout[i] = ynum[i] / denom[i] + cy[0];
}

extern "C" void kernel_launch(void* const* d_in, const int* in_sizes, int n_in,
                              void* d_out, int out_size, void* d_ws, size_t ws_size,
                              hipStream_t stream) {
    const float* input  = (const float*)d_in[0];
    const float* hidden = (const float*)d_in[1];
    const float* cell   = (const float*)d_in[2];
    const float* pre_w  = (const float*)d_in[3];
    const float* pre_b  = (const float*)d_in[4];
    const float* w_ih   = (const float*)d_in[5];
    const float* w_hh   = (const float*)d_in[6];
    const float* b_ih   = (const float*)d_in[7];
    const float* b_hh   = (const float*)d_in[8];
    const float* wsrc   = (const float*)d_in[9];
    const float* wdst   = (const float*)d_in[10];
    const float* attn   = (const float*)d_in[11];
    const float* gatb   = (const float*)d_in[12];
    const float* outw   = (const float*)d_in[13];
    const float* outb   = (const float*)d_in[14];
    const int*   esrc   = (const int*)d_in[15];
    const int*   edst   = (const int*)d_in[16];
    int nE = in_sizes[15];
    float* dout = (float*)d_out;
    char* ws = (char*)d_ws;

    // workspace layout (bytes, 256-aligned)
    const size_t o_xw    = 0;                 // 32768*512*2  = 33,554,432
    const size_t o_outs  = 33554432;          // 32768*128*4  = 16,777,216
    const size_t o_fs    = 50331648;          // 32768*128*2  =  8,388,608
    const size_t o_fd    = 58720256;          //               8,388,608
    const size_t o_fso   = 67108864;          // 32768*4      =    131,072
    const size_t o_denom = 67239936;          //    131,072
    const size_t o_ynum  = 67371008;          //    131,072
    const size_t o_wc    = 67502080;          //    131,072
    const size_t o_bc    = 67633152;          //      2,048
    const size_t o_wsT   = 67635200;          //     65,536
    const size_t o_wdT   = 67700736;          //     65,536
    const size_t o_wso   = 67766272;          //        512
    const size_t o_cy    = 67766784;          //          4
    const size_t o_whhb  = o_fs;              // overlaps fs (disjoint in time)

    bf16*  xw    = (bf16*)(ws + o_xw);
    float* outs  = (float*)(ws + o_outs);
    bf16*  fs    = (bf16*)(ws + o_fs);
    bf16*  fd    = (bf16*)(ws + o_fd);
    float* fso   = (float*)(ws + o_fso);
    float* denom = (float*)(ws + o_denom);
    float* ynum  = (float*)(ws + o_ynum);
    float* Wc    = (float*)(ws + o_wc);
    float* bc    = (float*)(ws + o_bc);
    float* wsT   = (float*)(ws + o_wsT);
    float* wdT   = (float*)(ws + o_wdT);
    float* wso   = (float*)(ws + o_wso);
    float* cy    = (float*)(ws + o_cy);
    bf16*  whhb  = (bf16*)(ws + o_whhb);

    prep_kernel<<<515, 256, 0, stream>>>(pre_w, pre_b, w_ih, b_ih, b_hh, w_hh, wsrc, wdst,
                                         outw, outb, gatb, Wc, bc, wsT, wdT, wso, cy, whhb);
    xw_kernel<<<2048, 512, 0, stream>>>(input, Wc, bc, xw);
    lstm_kernel<<<1, 512, 0, stream>>>(xw, whhb, hidden, cell, outs, dout);
    fsfd_kernel<<<1024, 256, 0, stream>>>(outs, wsT, wdT, fs, fd);
    fso_kernel<<<8192, 256, 0, stream>>>(outs, wso, fso);
    hipMemsetAsync(ws + o_denom, 0, 262144, stream);   // denom + ynum
    edge_kernel<<<(nE + 3) / 4, 256, 0, stream>>>(esrc, edst, fs, fd, attn, fso,
                                                  denom, ynum, nE);
    final_kernel<<<128, 256, 0, stream>>>(ynum, denom, cy, dout);
}

// Round 6
// 3652.205 us; speedup vs baseline: 1.3917x; 1.3917x over previous
//
#include <hip/hip_runtime.h>
#include <hip/hip_bf16.h>

#define N_NODES 4096
#define T_STEPS 8
#define INDIM   64
#define HDIM    128
#define G4      512                    // 4*H
#define NROWS   (N_NODES * T_STEPS)    // 32768

typedef __hip_bfloat16 bf16;
typedef __attribute__((ext_vector_type(8))) short bf16x8;
typedef __attribute__((ext_vector_type(4))) float f32x4;

__device__ __forceinline__ float bfbits2f(unsigned int u) {
    union { unsigned int i; float f; } v; v.i = u << 16; return v.f;
}
__device__ __forceinline__ unsigned int f2bfbits(float f) {
    bf16 b = __float2bfloat16(f);
    unsigned short u; __builtin_memcpy(&u, &b, 2); return (unsigned int)u;
}
// fast sigmoid on pre-negated input: in' = -x  ->  sigma(x) = rcp(1+e^{in'})
__device__ __forceinline__ float sigm_n(float xn) {
    return __builtin_amdgcn_rcpf(1.f + __expf(xn));
}
// fast tanh on pre-scaled input: in' = -2x -> tanh(x) = 2*rcp(1+e^{in'}) - 1
__device__ __forceinline__ float tanh_n(float xn2) {
    return fmaf(2.f, __builtin_amdgcn_rcpf(1.f + __expf(xn2)), -1.f);
}

// ---------------- K0: fold weights + bf16 conversions ------------------------
// Gate pre-scaling for fast transcendentals: rows of gates i,f,o scaled by -1,
// gate g rows scaled by -2 (applied to Wc, bc, whhb identically).
#define P_O0 32768
#define P_O1 (P_O0 + 512)
#define P_O2 (P_O1 + 16384)
#define P_O3 (P_O2 + 16384)
#define P_O4 (P_O3 + 128)
#define P_O5 (P_O4 + 1)
#define P_O6 (P_O5 + 65536)
__global__ void prep_kernel(const float* __restrict__ pre_w, const float* __restrict__ pre_b,
                            const float* __restrict__ w_ih, const float* __restrict__ b_ih,
                            const float* __restrict__ b_hh, const float* __restrict__ w_hh,
                            const float* __restrict__ wsrc, const float* __restrict__ wdst,
                            const float* __restrict__ out_w, const float* __restrict__ out_b,
                            const float* __restrict__ gat_b,
                            float* __restrict__ Wc, float* __restrict__ bc,
                            float* __restrict__ wsT, float* __restrict__ wdT,
                            float* __restrict__ wso, float* __restrict__ cy,
                            bf16* __restrict__ whhb) {
    int id = blockIdx.x * 256 + threadIdx.x;
    if (id < P_O0) {
        int g = id >> 6, i = id & 63;
        float s = 0.f;
        for (int k = 0; k < HDIM; k++) s += pre_w[i * HDIM + k] * w_ih[g * HDIM + k];
        int gate = g >> 7;
        Wc[id] = s * ((gate == 2) ? -2.f : -1.f);
    } else if (id < P_O1) {
        int g = id - P_O0;
        float s = b_ih[g] + b_hh[g];
        for (int k = 0; k < HDIM; k++) s += pre_b[k] * w_ih[g * HDIM + k];
        int gate = g >> 7;
        bc[g] = s * ((gate == 2) ? -2.f : -1.f);
    } else if (id < P_O2) {
        int c = id - P_O1;
        int co = c >> 7, k = c & 127;
        wsT[c] = wsrc[k * HDIM + co];
    } else if (id < P_O3) {
        int c = id - P_O2;
        int co = c >> 7, k = c & 127;
        wdT[c] = wdst[k * HDIM + co];
    } else if (id < P_O4) {
        int hi = id - P_O3;
        float s = 0.f;
        for (int ho = 0; ho < HDIM; ho++) s += wsrc[hi * HDIM + ho] * out_w[ho];
        wso[hi] = s;
    } else if (id == P_O4) {
        float s = out_b[0];
        for (int h = 0; h < HDIM; h++) s += gat_b[h] * out_w[h];
        cy[0] = s;
    } else if (id < P_O6) {
        int c = id - P_O5;
        int gate = c >> 14;                      // row = c>>7, gate = row>>7
        whhb[c] = __float2bfloat16(w_hh[c] * ((gate == 2) ? -2.f : -1.f));
    }
}

// ---------------- K1: xw[row][h*4+gate] = input[row,:64] . Wc[g,:] + bc[g] ---
// (gate-prescaled upstream; layout gate-interleaved per h -> one dwordx4/lane)
__global__ __launch_bounds__(512) void xw_kernel(const float* __restrict__ input,
                                                 const float* __restrict__ Wc,
                                                 const float* __restrict__ bc,
                                                 bf16* __restrict__ xw) {
    __shared__ __align__(16) float in_lds[16 * INDIM];   // 4KB: 16 rows
    int tid = threadIdx.x;
    int rowbase = blockIdx.x * 16;
    in_lds[tid]       = input[(size_t)rowbase * INDIM + tid];
    in_lds[tid + 512] = input[(size_t)rowbase * INDIM + tid + 512];
    __syncthreads();
    int g = tid;
    int gate = g >> 7, hh = g & 127;
    float4 w[16];
    const float4* wr = reinterpret_cast<const float4*>(Wc + g * INDIM);
#pragma unroll
    for (int u = 0; u < 16; u++) w[u] = wr[u];
    float b = bc[g];
    for (int r = 0; r < 16; r++) {
        const float4* hv = reinterpret_cast<const float4*>(in_lds + r * INDIM);
        float a0 = b, a1 = 0.f, a2 = 0.f, a3 = 0.f;
#pragma unroll
        for (int u = 0; u < 16; u++) {
            float4 h4 = hv[u]; float4 wv = w[u];
            a0 = fmaf(h4.x, wv.x, a0); a1 = fmaf(h4.y, wv.y, a1);
            a2 = fmaf(h4.z, wv.z, a2); a3 = fmaf(h4.w, wv.w, a3);
        }
        xw[(size_t)(rowbase + r) * G4 + hh * 4 + gate] = __float2bfloat16((a0 + a1) + (a2 + a3));
    }
}

// ---------------- K2: sequential LSTM scan, all 8 chains batched -------------
// 1 block, 512 threads (8 waves). B = [h^0 .. h^7] fills 8 MFMA columns
// (cols 8-15 mirror 0-7). Wave w owns gate tiles {w, 8+w, 16+w, 24+w} so a
// lane holds i,f,g,o of the same h in-register. 1 barrier/step (dbuf h),
// barrier does NOT drain vmcnt (raw s_barrier + lgkmcnt only).
__global__ __launch_bounds__(512, 1) void lstm_kernel(const bf16* __restrict__ xw,
                                                      const bf16* __restrict__ whhb,
                                                      const float* __restrict__ hidden0,
                                                      const float* __restrict__ cell0,
                                                      float* __restrict__ outs,
                                                      float* __restrict__ dout) {
    __shared__ __align__(16) char hbuf0[2048];   // h matrix [t][k] bf16, XOR-swizzled
    __shared__ __align__(16) char hbuf1[2048];
    const int tid  = threadIdx.x;
    const int w    = tid >> 6;
    const int lane = tid & 63;
    const int kg   = lane >> 4;        // 0..3
    const int lr   = lane & 15;
    const int t    = lr & 7;           // chain (MFMA column)
    const int rp   = lr >> 3;          // row-pair select within C regs
    const int hb   = 16 * w + kg * 4 + 2 * rp;   // first of this lane's 2 h indices

    // Persistent A fragments: gate G tile rows G*128+16w .. +16, all 4 K-tiles
    bf16x8 afr[4][4];
#pragma unroll
    for (int G = 0; G < 4; G++) {
        const unsigned short* rowp =
            reinterpret_cast<const unsigned short*>(whhb) + (size_t)(G * 128 + 16 * w + lr) * HDIM;
#pragma unroll
        for (int kt = 0; kt < 4; kt++)
            afr[G][kt] = *reinterpret_cast<const bf16x8*>(rowp + kt * 32 + kg * 8);
    }

    // swizzled LDS offsets (read: row t, bytes kt*64+kg*16; write: byte hb*2)
    const int boff0 = t * 256 + (((0 << 6) | (kg << 4)) ^ (t << 4));
    const int boff1 = t * 256 + (((1 << 6) | (kg << 4)) ^ (t << 4));
    const int boff2 = t * 256 + (((2 << 6) | (kg << 4)) ^ (t << 4));
    const int boff3 = t * 256 + (((3 << 6) | (kg << 4)) ^ (t << 4));
    const int woff  = t * 256 + ((hb * 2) ^ (t << 4));

    // init states
    float c0 = cell0[t * HDIM + hb];
    float c1 = cell0[t * HDIM + hb + 1];
    float h0v = hidden0[t * HDIM + hb];
    float h1v = hidden0[t * HDIM + hb + 1];
    *reinterpret_cast<unsigned int*>(hbuf0 + woff) = (f2bfbits(h1v) << 16) | f2bfbits(h0v);

    // xw pointer: row (n*8+t), bytes (h*4+gate)*2 -> t*1024 + hb*8 (+ n*8192)
    const uint4* xptr = reinterpret_cast<const uint4*>(
        reinterpret_cast<const char*>(xw) + (size_t)t * 1024 + (size_t)hb * 8);
    float* outp = outs + (size_t)t * HDIM + hb;

    uint4 xa = xptr[0];
    uint4 xb = xptr[512];
    __syncthreads();

#define STEPX(NIDX, RB, WB, XQ)                                                      \
    do {                                                                             \
        bf16x8 bfr0 = *reinterpret_cast<const bf16x8*>(RB + boff0);                  \
        bf16x8 bfr1 = *reinterpret_cast<const bf16x8*>(RB + boff1);                  \
        bf16x8 bfr2 = *reinterpret_cast<const bf16x8*>(RB + boff2);                  \
        bf16x8 bfr3 = *reinterpret_cast<const bf16x8*>(RB + boff3);                  \
        f32x4 acc[4];                                                                \
        _Pragma("unroll")                                                            \
        for (int G = 0; G < 4; G++) {                                                \
            f32x4 a = {0.f, 0.f, 0.f, 0.f};                                          \
            a = __builtin_amdgcn_mfma_f32_16x16x32_bf16(afr[G][0], bfr0, a, 0, 0, 0);\
            a = __builtin_amdgcn_mfma_f32_16x16x32_bf16(afr[G][1], bfr1, a, 0, 0, 0);\
            a = __builtin_amdgcn_mfma_f32_16x16x32_bf16(afr[G][2], bfr2, a, 0, 0, 0);\
            a = __builtin_amdgcn_mfma_f32_16x16x32_bf16(afr[G][3], bfr3, a, 0, 0, 0);\
            acc[G] = a;                                                              \
        }                                                                            \
        float gi0 = (rp ? acc[0][2] : acc[0][0]) + bfbits2f((XQ).x & 0xffffu);       \
        float gf0 = (rp ? acc[1][2] : acc[1][0]) + bfbits2f((XQ).x >> 16);           \
        float gg0 = (rp ? acc[2][2] : acc[2][0]) + bfbits2f((XQ).y & 0xffffu);       \
        float go0 = (rp ? acc[3][2] : acc[3][0]) + bfbits2f((XQ).y >> 16);           \
        float gi1 = (rp ? acc[0][3] : acc[0][1]) + bfbits2f((XQ).z & 0xffffu);       \
        float gf1 = (rp ? acc[1][3] : acc[1][1]) + bfbits2f((XQ).z >> 16);           \
        float gg1 = (rp ? acc[2][3] : acc[2][1]) + bfbits2f((XQ).w & 0xffffu);       \
        float go1 = (rp ? acc[3][3] : acc[3][1]) + bfbits2f((XQ).w >> 16);           \
        c0 = sigm_n(gf0) * c0 + sigm_n(gi0) * tanh_n(gg0);                           \
        h0v = sigm_n(go0) * tanh_n(-2.f * c0);                                       \
        c1 = sigm_n(gf1) * c1 + sigm_n(gi1) * tanh_n(gg1);                           \
        h1v = sigm_n(go1) * tanh_n(-2.f * c1);                                       \
        *reinterpret_cast<unsigned int*>(WB + woff) =                                \
            (f2bfbits(h1v) << 16) | f2bfbits(h0v);                                   \
        float2 o2; o2.x = h0v; o2.y = h1v;                                           \
        *reinterpret_cast<float2*>(outp + (size_t)(NIDX) * 1024) = o2;               \
        asm volatile("s_waitcnt lgkmcnt(0)" ::: "memory");                           \
        __builtin_amdgcn_s_barrier();                                                \
        __builtin_amdgcn_sched_barrier(0);                                           \
    } while (0)

    for (int n = 0; n < N_NODES; n += 2) {
        uint4 xc = {0, 0, 0, 0}, xd = {0, 0, 0, 0};
        if (n + 2 < N_NODES) {
            xc = xptr[(size_t)(n + 2) * 512];
            xd = xptr[(size_t)(n + 3) * 512];
        }
        STEPX(n,     hbuf0, hbuf1, xa);
        STEPX(n + 1, hbuf1, hbuf0, xb);
        xa = xc; xb = xd;
    }
#undef STEPX

    float2 hv; hv.x = h0v; hv.y = h1v;
    float2 cv; cv.x = c0;  cv.y = c1;
    *reinterpret_cast<float2*>(dout + NROWS + t * HDIM + hb) = hv;
    *reinterpret_cast<float2*>(dout + NROWS + T_STEPS * HDIM + t * HDIM + hb) = cv;
}

// ---------------- K3: fs = outs@wsrc, fd = outs@wdst (bf16 out) --------------
__global__ __launch_bounds__(256) void fsfd_kernel(const float* __restrict__ outs,
                                                   const float* __restrict__ wsT,
                                                   const float* __restrict__ wdT,
                                                   bf16* __restrict__ fs,
                                                   bf16* __restrict__ fd) {
    __shared__ __align__(16) float rows[32 * HDIM];    // 16KB: 32 rows
    int tid = threadIdx.x;
    size_t base = (size_t)blockIdx.x * 32 * HDIM;
#pragma unroll
    for (int j = 0; j < 16; j++) rows[tid + j * 256] = outs[base + tid + j * 256];
    __syncthreads();
    int c = tid;
    const float4* wT = reinterpret_cast<const float4*>(
        (c < HDIM) ? (wsT + c * HDIM) : (wdT + (c - HDIM) * HDIM));
    float4 w[32];
#pragma unroll
    for (int u = 0; u < 32; u++) w[u] = wT[u];
    bf16* dst = (c < HDIM) ? (fs + base + c) : (fd + base + (c - HDIM));
    for (int r = 0; r < 32; r++) {
        const float4* hv = reinterpret_cast<const float4*>(rows + r * HDIM);
        float a0 = 0.f, a1 = 0.f, a2 = 0.f, a3 = 0.f;
#pragma unroll
        for (int u = 0; u < 32; u++) {
            float4 h4 = hv[u]; float4 wv = w[u];
            a0 = fmaf(h4.x, wv.x, a0); a1 = fmaf(h4.y, wv.y, a1);
            a2 = fmaf(h4.z, wv.z, a2); a3 = fmaf(h4.w, wv.w, a3);
        }
        dst[(size_t)r * HDIM] = __float2bfloat16((a0 + a1) + (a2 + a3));
    }
}

// ---------------- K3b: fso[row] = outs[row,:] . wso --------------------------
__global__ __launch_bounds__(256) void fso_kernel(const float* __restrict__ outs,
                                                  const float* __restrict__ wso,
                                                  float* __restrict__ fso) {
    int tid = threadIdx.x;
    int l = tid & 63;
    int row = blockIdx.x * 4 + (tid >> 6);
    float v = outs[(size_t)row * HDIM + l] * wso[l]
            + outs[(size_t)row * HDIM + 64 + l] * wso[64 + l];
#pragma unroll
    for (int m = 32; m >= 1; m >>= 1) v += __shfl_xor(v, m, 64);
    if (l == 0) fso[row] = v;
}

// ---------------- K4: per-edge softmax numerators ----------------------------
__global__ __launch_bounds__(256) void edge_kernel(const int* __restrict__ esrc,
                                                   const int* __restrict__ edst,
                                                   const bf16* __restrict__ fs,
                                                   const bf16* __restrict__ fd,
                                                   const float* __restrict__ attn,
                                                   const float* __restrict__ fso,
                                                   float* __restrict__ denom,
                                                   float* __restrict__ ynum, int nE) {
    int tid = threadIdx.x;
    int l = tid & 63;
    int e = blockIdx.x * 4 + (tid >> 6);
    if (e >= nE) return;
    int s = esrc[e], d = edst[e];
    float at1 = attn[l], at2 = attn[64 + l];
    const bf16* fsr = fs + (size_t)s * (T_STEPS * HDIM);
    const bf16* fdr = fd + (size_t)d * (T_STEPS * HDIM);
#pragma unroll
    for (int t = 0; t < T_STEPS; t++) {
        float x1 = __bfloat162float(fsr[t * HDIM + l]) + __bfloat162float(fdr[t * HDIM + l]);
        float x2 = __bfloat162float(fsr[t * HDIM + 64 + l]) + __bfloat162float(fdr[t * HDIM + 64 + l]);
        x1 = fmaxf(x1, 0.f) + 0.2f * fminf(x1, 0.f);
        x2 = fmaxf(x2, 0.f) + 0.2f * fminf(x2, 0.f);
        float v = x1 * at1 + x2 * at2;
#pragma unroll
        for (int m = 32; m >= 1; m >>= 1) v += __shfl_xor(v, m, 64);
        if (l == 0) {
            float a = __expf(v);
            atomicAdd(&denom[d * T_STEPS + t], a);
            atomicAdd(&ynum[d * T_STEPS + t], a * fso[s * T_STEPS + t]);
        }
    }
}

// ---------------- K5: finalize y ---------------------------------------------
__global__ void final_kernel(const float* __restrict__ ynum, const float* __restrict__ denom,
                             const float* __restrict__ cy, float* __restrict__ dout) {
    int i = blockIdx.x * 256 + threadIdx.x;
    if (i < NROWS) dout[i] = ynum[i] / denom[i] + cy[0];
}

extern "C" void kernel_launch(void* const* d_in, const int* in_sizes, int n_in,
                              void* d_out, int out_size, void* d_ws, size_t ws_size,
                              hipStream_t stream) {
    const float* input  = (const float*)d_in[0];
    const float* hidden = (const float*)d_in[1];
    const float* cell   = (const float*)d_in[2];
    const float* pre_w  = (const float*)d_in[3];
    const float* pre_b  = (const float*)d_in[4];
    const float* w_ih   = (const float*)d_in[5];
    const float* w_hh   = (const float*)d_in[6];
    const float* b_ih   = (const float*)d_in[7];
    const float* b_hh   = (const float*)d_in[8];
    const float* wsrc   = (const float*)d_in[9];
    const float* wdst   = (const float*)d_in[10];
    const float* attn   = (const float*)d_in[11];
    const float* gatb   = (const float*)d_in[12];
    const float* outw   = (const float*)d_in[13];
    const float* outb   = (const float*)d_in[14];
    const int*   esrc   = (const int*)d_in[15];
    const int*   edst   = (const int*)d_in[16];
    int nE = in_sizes[15];
    float* dout = (float*)d_out;
    char* ws = (char*)d_ws;

    // workspace layout (bytes, 256-aligned)
    const size_t o_xw    = 0;                 // 32768*512*2  = 33,554,432
    const size_t o_outs  = 33554432;          // 32768*128*4  = 16,777,216
    const size_t o_fs    = 50331648;          // 32768*128*2  =  8,388,608
    const size_t o_fd    = 58720256;          //               8,388,608
    const size_t o_fso   = 67108864;          // 32768*4      =    131,072
    const size_t o_denom = 67239936;          //    131,072
    const size_t o_ynum  = 67371008;          //    131,072
    const size_t o_wc    = 67502080;          //    131,072
    const size_t o_bc    = 67633152;          //      2,048
    const size_t o_wsT   = 67635200;          //     65,536
    const size_t o_wdT   = 67700736;          //     65,536
    const size_t o_wso   = 67766272;          //        512
    const size_t o_cy    = 67766784;          //          4
    const size_t o_whhb  = o_fs;              // overlaps fs (disjoint in time)

    bf16*  xw    = (bf16*)(ws + o_xw);
    float* outs  = (float*)(ws + o_outs);
    bf16*  fs    = (bf16*)(ws + o_fs);
    bf16*  fd    = (bf16*)(ws + o_fd);
    float* fso   = (float*)(ws + o_fso);
    float* denom = (float*)(ws + o_denom);
    float* ynum  = (float*)(ws + o_ynum);
    float* Wc    = (float*)(ws + o_wc);
    float* bc    = (float*)(ws + o_bc);
    float* wsT   = (float*)(ws + o_wsT);
    float* wdT   = (float*)(ws + o_wdT);
    float* wso   = (float*)(ws + o_wso);
    float* cy    = (float*)(ws + o_cy);
    bf16*  whhb  = (bf16*)(ws + o_whhb);

    prep_kernel<<<515, 256, 0, stream>>>(pre_w, pre_b, w_ih, b_ih, b_hh, w_hh, wsrc, wdst,
                                         outw, outb, gatb, Wc, bc, wsT, wdT, wso, cy, whhb);
    xw_kernel<<<2048, 512, 0, stream>>>(input, Wc, bc, xw);
    lstm_kernel<<<1, 512, 0, stream>>>(xw, whhb, hidden, cell, outs, dout);
    fsfd_kernel<<<1024, 256, 0, stream>>>(outs, wsT, wdT, fs, fd);
    fso_kernel<<<8192, 256, 0, stream>>>(outs, wso, fso);
    hipMemsetAsync(ws + o_denom, 0, 262144, stream);   // denom + ynum
    edge_kernel<<<(nE + 3) / 4, 256, 0, stream>>>(esrc, edst, fs, fd, attn, fso,
                                                  denom, ynum, nE);
    final_kernel<<<128, 256, 0, stream>>>(ynum, denom, cy, dout);
}

// Round 7
// 2063.232 us; speedup vs baseline: 2.4636x; 1.7701x over previous
//
#include <hip/hip_runtime.h>
#include <hip/hip_bf16.h>

#define N_NODES 4096
#define T_STEPS 8
#define INDIM   64
#define HDIM    128
#define G4      512                    // 4*H
#define NROWS   (N_NODES * T_STEPS)    // 32768

typedef __hip_bfloat16 bf16;
typedef __attribute__((ext_vector_type(8))) short bf16x8;
typedef __attribute__((ext_vector_type(4))) float f32x4;

__device__ __forceinline__ float asfloat_u(unsigned int u) {
    union { unsigned int i; float f; } v; v.i = u; return v.f;
}

// ---------------- K0: fold weights + bf16 conversions ------------------------
// Gate pre-scaling for fast transcendentals: rows of gates i,f,o scaled by -1,
// gate g rows scaled by -2 (applied to Wc, bc, whhb identically).
#define P_O0 32768
#define P_O1 (P_O0 + 512)
#define P_O2 (P_O1 + 16384)
#define P_O3 (P_O2 + 16384)
#define P_O4 (P_O3 + 128)
#define P_O5 (P_O4 + 1)
#define P_O6 (P_O5 + 65536)
__global__ void prep_kernel(const float* __restrict__ pre_w, const float* __restrict__ pre_b,
                            const float* __restrict__ w_ih, const float* __restrict__ b_ih,
                            const float* __restrict__ b_hh, const float* __restrict__ w_hh,
                            const float* __restrict__ wsrc, const float* __restrict__ wdst,
                            const float* __restrict__ out_w, const float* __restrict__ out_b,
                            const float* __restrict__ gat_b,
                            float* __restrict__ Wc, float* __restrict__ bc,
                            float* __restrict__ wsT, float* __restrict__ wdT,
                            float* __restrict__ wso, float* __restrict__ cy,
                            bf16* __restrict__ whhb) {
    int id = blockIdx.x * 256 + threadIdx.x;
    if (id < P_O0) {
        int g = id >> 6, i = id & 63;
        float s = 0.f;
        for (int k = 0; k < HDIM; k++) s += pre_w[i * HDIM + k] * w_ih[g * HDIM + k];
        int gate = g >> 7;
        Wc[id] = s * ((gate == 2) ? -2.f : -1.f);
    } else if (id < P_O1) {
        int g = id - P_O0;
        float s = b_ih[g] + b_hh[g];
        for (int k = 0; k < HDIM; k++) s += pre_b[k] * w_ih[g * HDIM + k];
        int gate = g >> 7;
        bc[g] = s * ((gate == 2) ? -2.f : -1.f);
    } else if (id < P_O2) {
        int c = id - P_O1;
        int co = c >> 7, k = c & 127;
        wsT[c] = wsrc[k * HDIM + co];
    } else if (id < P_O3) {
        int c = id - P_O2;
        int co = c >> 7, k = c & 127;
        wdT[c] = wdst[k * HDIM + co];
    } else if (id < P_O4) {
        int hi = id - P_O3;
        float s = 0.f;
        for (int ho = 0; ho < HDIM; ho++) s += wsrc[hi * HDIM + ho] * out_w[ho];
        wso[hi] = s;
    } else if (id == P_O4) {
        float s = out_b[0];
        for (int h = 0; h < HDIM; h++) s += gat_b[h] * out_w[h];
        cy[0] = s;
    } else if (id < P_O6) {
        int c = id - P_O5;
        int gate = c >> 14;                      // row = c>>7, gate = row>>7
        whhb[c] = __float2bfloat16(w_hh[c] * ((gate == 2) ? -2.f : -1.f));
    }
}

// ---------------- K1: xw[row][h*4+gate] = input[row,:64] . Wc[g,:] + bc[g] ---
// (gate-prescaled upstream; layout gate-interleaved per h -> one dwordx2/lane)
__global__ __launch_bounds__(512) void xw_kernel(const float* __restrict__ input,
                                                 const float* __restrict__ Wc,
                                                 const float* __restrict__ bc,
                                                 bf16* __restrict__ xw) {
    __shared__ __align__(16) float in_lds[16 * INDIM];   // 4KB: 16 rows
    int tid = threadIdx.x;
    int rowbase = blockIdx.x * 16;
    in_lds[tid]       = input[(size_t)rowbase * INDIM + tid];
    in_lds[tid + 512] = input[(size_t)rowbase * INDIM + tid + 512];
    __syncthreads();
    int g = tid;
    int gate = g >> 7, hh = g & 127;
    float4 w[16];
    const float4* wr = reinterpret_cast<const float4*>(Wc + g * INDIM);
#pragma unroll
    for (int u = 0; u < 16; u++) w[u] = wr[u];
    float b = bc[g];
    for (int r = 0; r < 16; r++) {
        const float4* hv = reinterpret_cast<const float4*>(in_lds + r * INDIM);
        float a0 = b, a1 = 0.f, a2 = 0.f, a3 = 0.f;
#pragma unroll
        for (int u = 0; u < 16; u++) {
            float4 h4 = hv[u]; float4 wv = w[u];
            a0 = fmaf(h4.x, wv.x, a0); a1 = fmaf(h4.y, wv.y, a1);
            a2 = fmaf(h4.z, wv.z, a2); a3 = fmaf(h4.w, wv.w, a3);
        }
        xw[(size_t)(rowbase + r) * G4 + hh * 4 + gate] = __float2bfloat16((a0 + a1) + (a2 + a3));
    }
}

// ---------------- K2: sequential LSTM scan, 4 chains per block, 2 blocks -----
// Block b owns chains 4b..4b+3. 512 threads (8 waves). B cols = 4 chains x4 dup.
// Wave w owns gate tiles {w, 8+w, 16+w, 24+w}; lane (kg,lr) processes ONE h:
// chain q=lr&3, acc-reg d=lr>>2 -> h row = 16w + kg*4 + d. Gate i,f,g,o all
// in-lane (one per G-tile). 1 barrier/step (dbuf h), vmcnt never drained.
__global__ __launch_bounds__(512, 1) void lstm_kernel(const bf16* __restrict__ xw,
                                                      const bf16* __restrict__ whhb,
                                                      const float* __restrict__ hidden0,
                                                      const float* __restrict__ cell0,
                                                      float* __restrict__ outs,
                                                      float* __restrict__ dout) {
    // h matrix [4 chains][128] bf16, chain stride 288 B (bank-spread, 16B-aligned)
    __shared__ __align__(16) char hbuf0[4 * 288];
    __shared__ __align__(16) char hbuf1[4 * 288];
    const int tid  = threadIdx.x;
    const int w    = tid >> 6;
    const int lane = tid & 63;
    const int kg   = lane >> 4;        // 0..3 (k-group; also C-row block)
    const int lr   = lane & 15;        // A/C row-in-tile; C col
    const int q    = lr & 3;           // chain within block
    const int d    = lr >> 2;          // which C reg this lane consumes
    const int qg   = blockIdx.x * 4 + q;          // global chain (t)
    const int hb   = 16 * w + kg * 4 + d;         // this lane's h index

    // Persistent A fragments: gate G tile rows G*128+16w .. +16, all 4 K-tiles
    bf16x8 afr[4][4];
#pragma unroll
    for (int G = 0; G < 4; G++) {
        const unsigned short* rowp =
            reinterpret_cast<const unsigned short*>(whhb) + (size_t)(G * 128 + 16 * w + lr) * HDIM;
#pragma unroll
        for (int kt = 0; kt < 4; kt++)
            afr[G][kt] = *reinterpret_cast<const bf16x8*>(rowp + kt * 32 + kg * 8);
    }

    const int roff = q * 288 + kg * 16;   // B-frag read base (+ kt*64)
    const int woff = q * 288 + hb * 2;    // h write (b16)

    // init states
    float cv = cell0[qg * HDIM + hb];
    float hv = hidden0[qg * HDIM + hb];
    *reinterpret_cast<bf16*>(hbuf0 + woff) = __float2bfloat16(hv);

    // xw: row (n*8+qg), this h's 4 gates = 8 bytes -> uint2 idx row*128 + hb
    const uint2* xq = reinterpret_cast<const uint2*>(xw) + qg * 128 + hb;
    float* outp = outs + qg * HDIM + hb;

    uint2 xb[8];
#pragma unroll
    for (int i = 0; i < 8; i++) xb[i] = xq[i * 1024];
    __syncthreads();

#define STEPX(NIDX, RB, WB, XQ)                                                      \
    do {                                                                             \
        bf16x8 b0 = *reinterpret_cast<const bf16x8*>(RB + roff);                     \
        bf16x8 b1 = *reinterpret_cast<const bf16x8*>(RB + roff + 64);                \
        bf16x8 b2 = *reinterpret_cast<const bf16x8*>(RB + roff + 128);               \
        bf16x8 b3 = *reinterpret_cast<const bf16x8*>(RB + roff + 192);               \
        f32x4 acc[4];                                                                \
        _Pragma("unroll")                                                            \
        for (int G = 0; G < 4; G++) {                                                \
            f32x4 a = {0.f, 0.f, 0.f, 0.f};                                          \
            a = __builtin_amdgcn_mfma_f32_16x16x32_bf16(afr[G][0], b0, a, 0, 0, 0);  \
            a = __builtin_amdgcn_mfma_f32_16x16x32_bf16(afr[G][1], b1, a, 0, 0, 0);  \
            a = __builtin_amdgcn_mfma_f32_16x16x32_bf16(afr[G][2], b2, a, 0, 0, 0);  \
            a = __builtin_amdgcn_mfma_f32_16x16x32_bf16(afr[G][3], b3, a, 0, 0, 0);  \
            acc[G] = a;                                                              \
        }                                                                            \
        float s0 = (d & 2) ? ((d & 1) ? acc[0][3] : acc[0][2])                       \
                           : ((d & 1) ? acc[0][1] : acc[0][0]);                      \
        float s1 = (d & 2) ? ((d & 1) ? acc[1][3] : acc[1][2])                       \
                           : ((d & 1) ? acc[1][1] : acc[1][0]);                      \
        float s2 = (d & 2) ? ((d & 1) ? acc[2][3] : acc[2][2])                       \
                           : ((d & 1) ? acc[2][1] : acc[2][0]);                      \
        float s3 = (d & 2) ? ((d & 1) ? acc[3][3] : acc[3][2])                       \
                           : ((d & 1) ? acc[3][1] : acc[3][0]);                      \
        float gi = s0 + asfloat_u((XQ).x << 16);                                     \
        float gf = s1 + asfloat_u((XQ).x & 0xffff0000u);                             \
        float gg = s2 + asfloat_u((XQ).y << 16);                                     \
        float go = s3 + asfloat_u((XQ).y & 0xffff0000u);                             \
        float A = __expf(gi), C = __expf(gf), B = __expf(gg);                        \
        float p = 1.f + A, r = 1.f + B, s = 1.f + C;                                 \
        float pr = p * r;                                                            \
        float num = fmaf(cv, pr, (2.f - r) * s);                                     \
        cv = num * __builtin_amdgcn_rcpf(pr * s);                                    \
        float O = __expf(go), F = __expf(-2.f * cv);                                 \
        float po = 1.f + O, rf = 1.f + F;                                            \
        hv = (2.f - rf) * __builtin_amdgcn_rcpf(po * rf);                            \
        *reinterpret_cast<bf16*>(WB + woff) = __float2bfloat16(hv);                  \
        outp[(NIDX) * 1024] = hv;                                                    \
        asm volatile("s_waitcnt lgkmcnt(0)" ::: "memory");                           \
        __builtin_amdgcn_s_barrier();                                                \
        __builtin_amdgcn_sched_barrier(0);                                           \
    } while (0)

    for (int n = 0; n < N_NODES; n += 8) {
#pragma unroll
        for (int i = 0; i < 8; i++) {
            if (i & 1) STEPX(n + i, hbuf1, hbuf0, xb[i]);
            else       STEPX(n + i, hbuf0, hbuf1, xb[i]);
            // reload 8 steps ahead; tail reads land in outs region (in-bounds,
            // never consumed) so no conditionals needed
            xb[i] = xq[(n + i + 8) * 1024];
        }
    }
#undef STEPX

    dout[NROWS + qg * HDIM + hb] = hv;                        // hT
    dout[NROWS + T_STEPS * HDIM + qg * HDIM + hb] = cv;       // cT
}

// ---------------- K3: fs = outs@wsrc, fd = outs@wdst (bf16 out) --------------
__global__ __launch_bounds__(256) void fsfd_kernel(const float* __restrict__ outs,
                                                   const float* __restrict__ wsT,
                                                   const float* __restrict__ wdT,
                                                   bf16* __restrict__ fs,
                                                   bf16* __restrict__ fd) {
    __shared__ __align__(16) float rows[32 * HDIM];    // 16KB: 32 rows
    int tid = threadIdx.x;
    size_t base = (size_t)blockIdx.x * 32 * HDIM;
#pragma unroll
    for (int j = 0; j < 16; j++) rows[tid + j * 256] = outs[base + tid + j * 256];
    __syncthreads();
    int c = tid;
    const float4* wT = reinterpret_cast<const float4*>(
        (c < HDIM) ? (wsT + c * HDIM) : (wdT + (c - HDIM) * HDIM));
    float4 w[32];
#pragma unroll
    for (int u = 0; u < 32; u++) w[u] = wT[u];
    bf16* dst = (c < HDIM) ? (fs + base + c) : (fd + base + (c - HDIM));
    for (int r = 0; r < 32; r++) {
        const float4* hv = reinterpret_cast<const float4*>(rows + r * HDIM);
        float a0 = 0.f, a1 = 0.f, a2 = 0.f, a3 = 0.f;
#pragma unroll
        for (int u = 0; u < 32; u++) {
            float4 h4 = hv[u]; float4 wv = w[u];
            a0 = fmaf(h4.x, wv.x, a0); a1 = fmaf(h4.y, wv.y, a1);
            a2 = fmaf(h4.z, wv.z, a2); a3 = fmaf(h4.w, wv.w, a3);
        }
        dst[(size_t)r * HDIM] = __float2bfloat16((a0 + a1) + (a2 + a3));
    }
}

// ---------------- K3b: fso[row] = outs[row,:] . wso --------------------------
__global__ __launch_bounds__(256) void fso_kernel(const float* __restrict__ outs,
                                                  const float* __restrict__ wso,
                                                  float* __restrict__ fso) {
    int tid = threadIdx.x;
    int l = tid & 63;
    int row = blockIdx.x * 4 + (tid >> 6);
    float v = outs[(size_t)row * HDIM + l] * wso[l]
            + outs[(size_t)row * HDIM + 64 + l] * wso[64 + l];
#pragma unroll
    for (int m = 32; m >= 1; m >>= 1) v += __shfl_xor(v, m, 64);
    if (l == 0) fso[row] = v;
}

// ---------------- K4: per-edge softmax numerators ----------------------------
__global__ __launch_bounds__(256) void edge_kernel(const int* __restrict__ esrc,
                                                   const int* __restrict__ edst,
                                                   const bf16* __restrict__ fs,
                                                   const bf16* __restrict__ fd,
                                                   const float* __restrict__ attn,
                                                   const float* __restrict__ fso,
                                                   float* __restrict__ denom,
                                                   float* __restrict__ ynum, int nE) {
    int tid = threadIdx.x;
    int l = tid & 63;
    int e = blockIdx.x * 4 + (tid >> 6);
    if (e >= nE) return;
    int s = esrc[e], d = edst[e];
    float at1 = attn[l], at2 = attn[64 + l];
    const bf16* fsr = fs + (size_t)s * (T_STEPS * HDIM);
    const bf16* fdr = fd + (size_t)d * (T_STEPS * HDIM);
#pragma unroll
    for (int t = 0; t < T_STEPS; t++) {
        float x1 = __bfloat162float(fsr[t * HDIM + l]) + __bfloat162float(fdr[t * HDIM + l]);
        float x2 = __bfloat162float(fsr[t * HDIM + 64 + l]) + __bfloat162float(fdr[t * HDIM + 64 + l]);
        x1 = fmaxf(x1, 0.f) + 0.2f * fminf(x1, 0.f);
        x2 = fmaxf(x2, 0.f) + 0.2f * fminf(x2, 0.f);
        float v = x1 * at1 + x2 * at2;
#pragma unroll
        for (int m = 32; m >= 1; m >>= 1) v += __shfl_xor(v, m, 64);
        if (l == 0) {
            float a = __expf(v);
            atomicAdd(&denom[d * T_STEPS + t], a);
            atomicAdd(&ynum[d * T_STEPS + t], a * fso[s * T_STEPS + t]);
        }
    }
}

// ---------------- K5: finalize y ---------------------------------------------
__global__ void final_kernel(const float* __restrict__ ynum, const float* __restrict__ denom,
                             const float* __restrict__ cy, float* __restrict__ dout) {
    int i = blockIdx.x * 256 + threadIdx.x;
    if (i < NROWS) dout[i] = ynum[i] / denom[i] + cy[0];
}

extern "C" void kernel_launch(void* const* d_in, const int* in_sizes, int n_in,
                              void* d_out, int out_size, void* d_ws, size_t ws_size,
                              hipStream_t stream) {
    const float* input  = (const float*)d_in[0];
    const float* hidden = (const float*)d_in[1];
    const float* cell   = (const float*)d_in[2];
    const float* pre_w  = (const float*)d_in[3];
    const float* pre_b  = (const float*)d_in[4];
    const float* w_ih   = (const float*)d_in[5];
    const float* w_hh   = (const float*)d_in[6];
    const float* b_ih   = (const float*)d_in[7];
    const float* b_hh   = (const float*)d_in[8];
    const float* wsrc   = (const float*)d_in[9];
    const float* wdst   = (const float*)d_in[10];
    const float* attn   = (const float*)d_in[11];
    const float* gatb   = (const float*)d_in[12];
    const float* outw   = (const float*)d_in[13];
    const float* outb   = (const float*)d_in[14];
    const int*   esrc   = (const int*)d_in[15];
    const int*   edst   = (const int*)d_in[16];
    int nE = in_sizes[15];
    float* dout = (float*)d_out;
    char* ws = (char*)d_ws;

    // workspace layout (bytes, 256-aligned)
    const size_t o_xw    = 0;                 // 32768*512*2  = 33,554,432
    const size_t o_outs  = 33554432;          // 32768*128*4  = 16,777,216
    const size_t o_fs    = 50331648;          // 32768*128*2  =  8,388,608
    const size_t o_fd    = 58720256;          //               8,388,608
    const size_t o_fso   = 67108864;          // 32768*4      =    131,072
    const size_t o_denom = 67239936;          //    131,072
    const size_t o_ynum  = 67371008;          //    131,072
    const size_t o_wc    = 67502080;          //    131,072
    const size_t o_bc    = 67633152;          //      2,048
    const size_t o_wsT   = 67635200;          //     65,536
    const size_t o_wdT   = 67700736;          //     65,536
    const size_t o_wso   = 67766272;          //        512
    const size_t o_cy    = 67766784;          //          4
    const size_t o_whhb  = o_fs;              // overlaps fs (disjoint in time)

    bf16*  xw    = (bf16*)(ws + o_xw);
    float* outs  = (float*)(ws + o_outs);
    bf16*  fs    = (bf16*)(ws + o_fs);
    bf16*  fd    = (bf16*)(ws + o_fd);
    float* fso   = (float*)(ws + o_fso);
    float* denom = (float*)(ws + o_denom);
    float* ynum  = (float*)(ws + o_ynum);
    float* Wc    = (float*)(ws + o_wc);
    float* bc    = (float*)(ws + o_bc);
    float* wsT   = (float*)(ws + o_wsT);
    float* wdT   = (float*)(ws + o_wdT);
    float* wso   = (float*)(ws + o_wso);
    float* cy    = (float*)(ws + o_cy);
    bf16*  whhb  = (bf16*)(ws + o_whhb);

    prep_kernel<<<515, 256, 0, stream>>>(pre_w, pre_b, w_ih, b_ih, b_hh, w_hh, wsrc, wdst,
                                         outw, outb, gatb, Wc, bc, wsT, wdT, wso, cy, whhb);
    xw_kernel<<<2048, 512, 0, stream>>>(input, Wc, bc, xw);
    lstm_kernel<<<2, 512, 0, stream>>>(xw, whhb, hidden, cell, outs, dout);
    fsfd_kernel<<<1024, 256, 0, stream>>>(outs, wsT, wdT, fs, fd);
    fso_kernel<<<8192, 256, 0, stream>>>(outs, wso, fso);
    hipMemsetAsync(ws + o_denom, 0, 262144, stream);   // denom + ynum
    edge_kernel<<<(nE + 3) / 4, 256, 0, stream>>>(esrc, edst, fs, fd, attn, fso,
                                                  denom, ynum, nE);
    final_kernel<<<128, 256, 0, stream>>>(ynum, denom, cy, dout);
}

// Round 8
// 1973.632 us; speedup vs baseline: 2.5754x; 1.0454x over previous
//
#include <hip/hip_runtime.h>
#include <hip/hip_bf16.h>

#define N_NODES 4096
#define T_STEPS 8
#define INDIM   64
#define HDIM    128
#define G4      512                    // 4*H
#define NROWS   (N_NODES * T_STEPS)    // 32768
#define LOG2E   1.4426950408889634f

typedef __hip_bfloat16 bf16;
typedef __attribute__((ext_vector_type(8))) short bf16x8;
typedef __attribute__((ext_vector_type(4))) float f32x4;
typedef __attribute__((ext_vector_type(8))) int   i32x8;

__device__ __forceinline__ float asfloat_u(unsigned int u) {
    union { unsigned int i; float f; } v; v.i = u; return v.f;
}

// ---------------- K0: fold weights + fp8 conversions -------------------------
// Gate pre-scaling: gates i,f,o rows scaled by -log2e, gate g rows by -2*log2e
// (so device exp chains are bare v_exp_f32 = 2^x). Applied identically to
// Wc, bc (hence xw) and whh8. whh8 = fp8 e4m3 of scaled w_hh (512x128 bytes).
#define P_O0 32768
#define P_O1 (P_O0 + 512)
#define P_O2 (P_O1 + 16384)
#define P_O3 (P_O2 + 16384)
#define P_O4 (P_O3 + 128)
#define P_O5 (P_O4 + 1)
#define P_O6 (P_O5 + 65536)
__global__ void prep_kernel(const float* __restrict__ pre_w, const float* __restrict__ pre_b,
                            const float* __restrict__ w_ih, const float* __restrict__ b_ih,
                            const float* __restrict__ b_hh, const float* __restrict__ w_hh,
                            const float* __restrict__ wsrc, const float* __restrict__ wdst,
                            const float* __restrict__ out_w, const float* __restrict__ out_b,
                            const float* __restrict__ gat_b,
                            float* __restrict__ Wc, float* __restrict__ bc,
                            float* __restrict__ wsT, float* __restrict__ wdT,
                            float* __restrict__ wso, float* __restrict__ cy,
                            unsigned char* __restrict__ whh8) {
    int id = blockIdx.x * 256 + threadIdx.x;
    if (id < P_O0) {
        int g = id >> 6, i = id & 63;
        float s = 0.f;
        for (int k = 0; k < HDIM; k++) s += pre_w[i * HDIM + k] * w_ih[g * HDIM + k];
        int gate = g >> 7;
        Wc[id] = s * ((gate == 2) ? -2.f * LOG2E : -LOG2E);
    } else if (id < P_O1) {
        int g = id - P_O0;
        float s = b_ih[g] + b_hh[g];
        for (int k = 0; k < HDIM; k++) s += pre_b[k] * w_ih[g * HDIM + k];
        int gate = g >> 7;
        bc[g] = s * ((gate == 2) ? -2.f * LOG2E : -LOG2E);
    } else if (id < P_O2) {
        int c = id - P_O1;
        int co = c >> 7, k = c & 127;
        wsT[c] = wsrc[k * HDIM + co];
    } else if (id < P_O3) {
        int c = id - P_O2;
        int co = c >> 7, k = c & 127;
        wdT[c] = wdst[k * HDIM + co];
    } else if (id < P_O4) {
        int hi = id - P_O3;
        float s = 0.f;
        for (int ho = 0; ho < HDIM; ho++) s += wsrc[hi * HDIM + ho] * out_w[ho];
        wso[hi] = s;
    } else if (id == P_O4) {
        float s = out_b[0];
        for (int h = 0; h < HDIM; h++) s += gat_b[h] * out_w[h];
        cy[0] = s;
    } else if (id < P_O6) {
        int c = id - P_O5;
        int gate = c >> 14;                      // row = c>>7, gate = row>>7
        float v = w_hh[c] * ((gate == 2) ? -2.f * LOG2E : -LOG2E);
        int pk = __builtin_amdgcn_cvt_pk_fp8_f32(v, v, 0, false);
        whh8[c] = (unsigned char)(pk & 0xff);
    }
}

// ---------------- K1: xw[row][h*4+gate] = input[row,:64] . Wc[g,:] + bc[g] ---
// (gate- and log2e-prescaled upstream; gate-interleaved per h -> one uint2/lane)
__global__ __launch_bounds__(512) void xw_kernel(const float* __restrict__ input,
                                                 const float* __restrict__ Wc,
                                                 const float* __restrict__ bc,
                                                 bf16* __restrict__ xw) {
    __shared__ __align__(16) float in_lds[16 * INDIM];   // 4KB: 16 rows
    int tid = threadIdx.x;
    int rowbase = blockIdx.x * 16;
    in_lds[tid]       = input[(size_t)rowbase * INDIM + tid];
    in_lds[tid + 512] = input[(size_t)rowbase * INDIM + tid + 512];
    __syncthreads();
    int g = tid;
    int gate = g >> 7, hh = g & 127;
    float4 w[16];
    const float4* wr = reinterpret_cast<const float4*>(Wc + g * INDIM);
#pragma unroll
    for (int u = 0; u < 16; u++) w[u] = wr[u];
    float b = bc[g];
    for (int r = 0; r < 16; r++) {
        const float4* hv = reinterpret_cast<const float4*>(in_lds + r * INDIM);
        float a0 = b, a1 = 0.f, a2 = 0.f, a3 = 0.f;
#pragma unroll
        for (int u = 0; u < 16; u++) {
            float4 h4 = hv[u]; float4 wv = w[u];
            a0 = fmaf(h4.x, wv.x, a0); a1 = fmaf(h4.y, wv.y, a1);
            a2 = fmaf(h4.z, wv.z, a2); a3 = fmaf(h4.w, wv.w, a3);
        }
        xw[(size_t)(rowbase + r) * G4 + hh * 4 + gate] = __float2bfloat16((a0 + a1) + (a2 + a3));
    }
}

// ---------------- K2: sequential LSTM scan, 4 chains/block, 2 blocks ---------
// MX fp8 K=128 MFMA: one mfma_scale_f32_16x16x128_f8f6f4 per gate tile per
// step (4/wave, was 16). W_hh rows and the recurrent h vector are fp8 e4m3
// (scales pinned to 1.0 via e8m0=0x7F). Gate i,f,g,o in-lane; 1 barrier/step;
// vmcnt never drained in-loop.
__global__ __launch_bounds__(512, 1) void lstm_kernel(const bf16* __restrict__ xw,
                                                      const unsigned char* __restrict__ whh8,
                                                      const float* __restrict__ hidden0,
                                                      const float* __restrict__ cell0,
                                                      float* __restrict__ outs,
                                                      float* __restrict__ dout) {
    // h matrix [4 chains][128] fp8, chain stride 160 B (16B-aligned)
    __shared__ __align__(16) char hbuf0[4 * 160];
    __shared__ __align__(16) char hbuf1[4 * 160];
    const int tid  = threadIdx.x;
    const int w    = tid >> 6;
    const int lane = tid & 63;
    const int kg   = lane >> 4;        // 0..3 (k-group of 32; also C-row block)
    const int lr   = lane & 15;        // A-row in tile; C col
    const int q    = lr & 3;           // chain within block
    const int d    = lr >> 2;          // which C reg this lane consumes
    const int qg   = blockIdx.x * 4 + q;          // global chain (t)
    const int hb   = 16 * w + kg * 4 + d;         // this lane's h index

    // Persistent A fragments (fp8): gate G rows G*128+16w+lr, k-bytes kg*32..+32
    i32x8 afr[4];
#pragma unroll
    for (int G = 0; G < 4; G++) {
        const unsigned char* rowp = whh8 + (size_t)(G * 128 + 16 * w + lr) * HDIM + kg * 32;
        afr[G] = *reinterpret_cast<const i32x8*>(rowp);
    }

    const int roff = q * 160 + kg * 32;   // B-frag read base (32 contiguous bytes)
    const int woff = q * 160 + hb;        // h write (1 byte)
    const int sc   = 0x7f7f7f7f;          // e8m0 scale 1.0 in every byte

    // init states
    float cv = cell0[qg * HDIM + hb];
    float hv = hidden0[qg * HDIM + hb];
    {
        int pk = __builtin_amdgcn_cvt_pk_fp8_f32(hv, hv, 0, false);
        *reinterpret_cast<unsigned char*>(hbuf0 + woff) = (unsigned char)(pk & 0xff);
    }

    // xw: row (n*8+qg), this h's 4 gates = 8 bytes -> uint2 idx row*128 + hb
    const uint2* xq = reinterpret_cast<const uint2*>(xw) + qg * 128 + hb;
    float* outp = outs + qg * HDIM + hb;

    uint2 xb[8];
#pragma unroll
    for (int i = 0; i < 8; i++) xb[i] = xq[i * 1024];
    __syncthreads();

#define STEPX(NIDX, RB, WB, XQ)                                                      \
    do {                                                                             \
        i32x8 bfr = *reinterpret_cast<const i32x8*>(RB + roff);                      \
        f32x4 z = {0.f, 0.f, 0.f, 0.f};                                              \
        f32x4 acc0 = __builtin_amdgcn_mfma_scale_f32_16x16x128_f8f6f4(               \
            afr[0], bfr, z, 0, 0, 0, sc, 0, sc);                                     \
        f32x4 acc1 = __builtin_amdgcn_mfma_scale_f32_16x16x128_f8f6f4(               \
            afr[1], bfr, z, 0, 0, 0, sc, 0, sc);                                     \
        f32x4 acc2 = __builtin_amdgcn_mfma_scale_f32_16x16x128_f8f6f4(               \
            afr[2], bfr, z, 0, 0, 0, sc, 0, sc);                                     \
        f32x4 acc3 = __builtin_amdgcn_mfma_scale_f32_16x16x128_f8f6f4(               \
            afr[3], bfr, z, 0, 0, 0, sc, 0, sc);                                     \
        float s0 = (d & 2) ? ((d & 1) ? acc0[3] : acc0[2])                           \
                           : ((d & 1) ? acc0[1] : acc0[0]);                          \
        float s1 = (d & 2) ? ((d & 1) ? acc1[3] : acc1[2])                           \
                           : ((d & 1) ? acc1[1] : acc1[0]);                          \
        float s2 = (d & 2) ? ((d & 1) ? acc2[3] : acc2[2])                           \
                           : ((d & 1) ? acc2[1] : acc2[0]);                          \
        float s3 = (d & 2) ? ((d & 1) ? acc3[3] : acc3[2])                           \
                           : ((d & 1) ? acc3[1] : acc3[0]);                          \
        float gi = s0 + asfloat_u((XQ).x << 16);                                     \
        float gf = s1 + asfloat_u((XQ).x & 0xffff0000u);                             \
        float gg = s2 + asfloat_u((XQ).y << 16);                                     \
        float go = s3 + asfloat_u((XQ).y & 0xffff0000u);                             \
        float A = exp2f(gi), C = exp2f(gf), B = exp2f(gg);                           \
        float p = 1.f + A, r = 1.f + B, s = 1.f + C;                                 \
        float pr = p * r;                                                            \
        float num = fmaf(cv, pr, (2.f - r) * s);                                     \
        cv = num * __builtin_amdgcn_rcpf(pr * s);                                    \
        float O = exp2f(go), F = exp2f(cv * (-2.f * LOG2E));                         \
        float po = 1.f + O, rf = 1.f + F;                                            \
        hv = (2.f - rf) * __builtin_amdgcn_rcpf(po * rf);                            \
        int pk = __builtin_amdgcn_cvt_pk_fp8_f32(hv, hv, 0, false);                  \
        *reinterpret_cast<unsigned char*>(WB + woff) = (unsigned char)(pk & 0xff);   \
        outp[(NIDX) * 1024] = hv;                                                    \
        asm volatile("s_waitcnt lgkmcnt(0)" ::: "memory");                           \
        __builtin_amdgcn_s_barrier();                                                \
        __builtin_amdgcn_sched_barrier(0);                                           \
    } while (0)

    for (int n = 0; n < N_NODES; n += 8) {
#pragma unroll
        for (int i = 0; i < 8; i++) {
            if (i & 1) STEPX(n + i, hbuf1, hbuf0, xb[i]);
            else       STEPX(n + i, hbuf0, hbuf1, xb[i]);
            // reload 8 steps ahead; tail reads land in outs region (in-bounds,
            // never consumed) so no conditionals needed
            xb[i] = xq[(n + i + 8) * 1024];
        }
    }
#undef STEPX

    dout[NROWS + qg * HDIM + hb] = hv;                        // hT
    dout[NROWS + T_STEPS * HDIM + qg * HDIM + hb] = cv;       // cT
}

// ---------------- K3: fs = outs@wsrc, fd = outs@wdst (bf16 out) --------------
__global__ __launch_bounds__(256) void fsfd_kernel(const float* __restrict__ outs,
                                                   const float* __restrict__ wsT,
                                                   const float* __restrict__ wdT,
                                                   bf16* __restrict__ fs,
                                                   bf16* __restrict__ fd) {
    __shared__ __align__(16) float rows[32 * HDIM];    // 16KB: 32 rows
    int tid = threadIdx.x;
    size_t base = (size_t)blockIdx.x * 32 * HDIM;
#pragma unroll
    for (int j = 0; j < 16; j++) rows[tid + j * 256] = outs[base + tid + j * 256];
    __syncthreads();
    int c = tid;
    const float4* wT = reinterpret_cast<const float4*>(
        (c < HDIM) ? (wsT + c * HDIM) : (wdT + (c - HDIM) * HDIM));
    float4 w[32];
#pragma unroll
    for (int u = 0; u < 32; u++) w[u] = wT[u];
    bf16* dst = (c < HDIM) ? (fs + base + c) : (fd + base + (c - HDIM));
    for (int r = 0; r < 32; r++) {
        const float4* hv = reinterpret_cast<const float4*>(rows + r * HDIM);
        float a0 = 0.f, a1 = 0.f, a2 = 0.f, a3 = 0.f;
#pragma unroll
        for (int u = 0; u < 32; u++) {
            float4 h4 = hv[u]; float4 wv = w[u];
            a0 = fmaf(h4.x, wv.x, a0); a1 = fmaf(h4.y, wv.y, a1);
            a2 = fmaf(h4.z, wv.z, a2); a3 = fmaf(h4.w, wv.w, a3);
        }
        dst[(size_t)r * HDIM] = __float2bfloat16((a0 + a1) + (a2 + a3));
    }
}

// ---------------- K3b: fso[row] = outs[row,:] . wso --------------------------
__global__ __launch_bounds__(256) void fso_kernel(const float* __restrict__ outs,
                                                  const float* __restrict__ wso,
                                                  float* __restrict__ fso) {
    int tid = threadIdx.x;
    int l = tid & 63;
    int row = blockIdx.x * 4 + (tid >> 6);
    float v = outs[(size_t)row * HDIM + l] * wso[l]
            + outs[(size_t)row * HDIM + 64 + l] * wso[64 + l];
#pragma unroll
    for (int m = 32; m >= 1; m >>= 1) v += __shfl_xor(v, m, 64);
    if (l == 0) fso[row] = v;
}

// ---------------- K4: per-edge softmax numerators ----------------------------
__global__ __launch_bounds__(256) void edge_kernel(const int* __restrict__ esrc,
                                                   const int* __restrict__ edst,
                                                   const bf16* __restrict__ fs,
                                                   const bf16* __restrict__ fd,
                                                   const float* __restrict__ attn,
                                                   const float* __restrict__ fso,
                                                   float* __restrict__ denom,
                                                   float* __restrict__ ynum, int nE) {
    int tid = threadIdx.x;
    int l = tid & 63;
    int e = blockIdx.x * 4 + (tid >> 6);
    if (e >= nE) return;
    int s = esrc[e], d = edst[e];
    float at1 = attn[l], at2 = attn[64 + l];
    const bf16* fsr = fs + (size_t)s * (T_STEPS * HDIM);
    const bf16* fdr = fd + (size_t)d * (T_STEPS * HDIM);
#pragma unroll
    for (int t = 0; t < T_STEPS; t++) {
        float x1 = __bfloat162float(fsr[t * HDIM + l]) + __bfloat162float(fdr[t * HDIM + l]);
        float x2 = __bfloat162float(fsr[t * HDIM + 64 + l]) + __bfloat162float(fdr[t * HDIM + 64 + l]);
        x1 = fmaxf(x1, 0.f) + 0.2f * fminf(x1, 0.f);
        x2 = fmaxf(x2, 0.f) + 0.2f * fminf(x2, 0.f);
        float v = x1 * at1 + x2 * at2;
#pragma unroll
        for (int m = 32; m >= 1; m >>= 1) v += __shfl_xor(v, m, 64);
        if (l == 0) {
            float a = __expf(v);
            atomicAdd(&denom[d * T_STEPS + t], a);
            atomicAdd(&ynum[d * T_STEPS + t], a * fso[s * T_STEPS + t]);
        }
    }
}

// ---------------- K5: finalize y ---------------------------------------------
__global__ void final_kernel(const float* __restrict__ ynum, const float* __restrict__ denom,
                             const float* __restrict__ cy, float* __restrict__ dout) {
    int i = blockIdx.x * 256 + threadIdx.x;
    if (i < NROWS) dout[i] = ynum[i] / denom[i] + cy[0];
}

extern "C" void kernel_launch(void* const* d_in, const int* in_sizes, int n_in,
                              void* d_out, int out_size, void* d_ws, size_t ws_size,
                              hipStream_t stream) {
    const float* input  = (const float*)d_in[0];
    const float* hidden = (const float*)d_in[1];
    const float* cell   = (const float*)d_in[2];
    const float* pre_w  = (const float*)d_in[3];
    const float* pre_b  = (const float*)d_in[4];
    const float* w_ih   = (const float*)d_in[5];
    const float* w_hh   = (const float*)d_in[6];
    const float* b_ih   = (const float*)d_in[7];
    const float* b_hh   = (const float*)d_in[8];
    const float* wsrc   = (const float*)d_in[9];
    const float* wdst   = (const float*)d_in[10];
    const float* attn   = (const float*)d_in[11];
    const float* gatb   = (const float*)d_in[12];
    const float* outw   = (const float*)d_in[13];
    const float* outb   = (const float*)d_in[14];
    const int*   esrc   = (const int*)d_in[15];
    const int*   edst   = (const int*)d_in[16];
    int nE = in_sizes[15];
    float* dout = (float*)d_out;
    char* ws = (char*)d_ws;

    // workspace layout (bytes, 256-aligned)
    const size_t o_xw    = 0;                 // 32768*512*2  = 33,554,432
    const size_t o_outs  = 33554432;          // 32768*128*4  = 16,777,216
    const size_t o_fs    = 50331648;          // 32768*128*2  =  8,388,608
    const size_t o_fd    = 58720256;          //               8,388,608
    const size_t o_fso   = 67108864;          // 32768*4      =    131,072
    const size_t o_denom = 67239936;          //    131,072
    const size_t o_ynum  = 67371008;          //    131,072
    const size_t o_wc    = 67502080;          //    131,072
    const size_t o_bc    = 67633152;          //      2,048
    const size_t o_wsT   = 67635200;          //     65,536
    const size_t o_wdT   = 67700736;          //     65,536
    const size_t o_wso   = 67766272;          //        512
    const size_t o_cy    = 67766784;          //          4
    const size_t o_whh8  = o_fs;              // fp8 w_hh overlaps fs (disjoint in time)

    bf16*  xw    = (bf16*)(ws + o_xw);
    float* outs  = (float*)(ws + o_outs);
    bf16*  fs    = (bf16*)(ws + o_fs);
    bf16*  fd    = (bf16*)(ws + o_fd);
    float* fso   = (float*)(ws + o_fso);
    float* denom = (float*)(ws + o_denom);
    float* ynum  = (float*)(ws + o_ynum);
    float* Wc    = (float*)(ws + o_wc);
    float* bc    = (float*)(ws + o_bc);
    float* wsT   = (float*)(ws + o_wsT);
    float* wdT   = (float*)(ws + o_wdT);
    float* wso   = (float*)(ws + o_wso);
    float* cy    = (float*)(ws + o_cy);
    unsigned char* whh8 = (unsigned char*)(ws + o_whh8);

    prep_kernel<<<515, 256, 0, stream>>>(pre_w, pre_b, w_ih, b_ih, b_hh, w_hh, wsrc, wdst,
                                         outw, outb, gatb, Wc, bc, wsT, wdT, wso, cy, whh8);
    xw_kernel<<<2048, 512, 0, stream>>>(input, Wc, bc, xw);
    lstm_kernel<<<2, 512, 0, stream>>>(xw, whh8, hidden, cell, outs, dout);
    fsfd_kernel<<<1024, 256, 0, stream>>>(outs, wsT, wdT, fs, fd);
    fso_kernel<<<8192, 256, 0, stream>>>(outs, wso, fso);
    hipMemsetAsync(ws + o_denom, 0, 262144, stream);   // denom + ynum
    edge_kernel<<<(nE + 3) / 4, 256, 0, stream>>>(esrc, edst, fs, fd, attn, fso,
                                                  denom, ynum, nE);
    final_kernel<<<128, 256, 0, stream>>>(ynum, denom, cy, dout);
}

// Round 9
// 1692.772 us; speedup vs baseline: 3.0027x; 1.1659x over previous
//
#include <hip/hip_runtime.h>
#include <hip/hip_bf16.h>

#define N_NODES 4096
#define T_STEPS 8
#define INDIM   64
#define HDIM    128
#define G4      512                    // 4*H
#define NROWS   (N_NODES * T_STEPS)    // 32768
#define LOG2E   1.4426950408889634f

typedef __hip_bfloat16 bf16;
typedef __attribute__((ext_vector_type(8))) short bf16x8;
typedef __attribute__((ext_vector_type(4))) float f32x4;
typedef __attribute__((ext_vector_type(8))) int   i32x8;

__device__ __forceinline__ float asfloat_u(unsigned int u) {
    union { unsigned int i; float f; } v; v.i = u; return v.f;
}
// bare hardware exp2 (1 instr; OCML exp2f carries fixup code without fast-math)
__device__ __forceinline__ float fexp2(float x) {
    float r; asm("v_exp_f32 %0, %1" : "=v"(r) : "v"(x)); return r;
}

// ---------------- K0: fold weights + fp8 conversions -------------------------
// Gate pre-scaling: gates i,f,o rows scaled by -log2e, gate g rows by -2*log2e
// (so device exp chains are bare v_exp_f32 = 2^x). Applied identically to
// Wc, bc (hence xw) and whh8. whh8 = fp8 e4m3 of scaled w_hh (512x128 bytes).
#define P_O0 32768
#define P_O1 (P_O0 + 512)
#define P_O2 (P_O1 + 16384)
#define P_O3 (P_O2 + 16384)
#define P_O4 (P_O3 + 128)
#define P_O5 (P_O4 + 1)
#define P_O6 (P_O5 + 65536)
__global__ void prep_kernel(const float* __restrict__ pre_w, const float* __restrict__ pre_b,
                            const float* __restrict__ w_ih, const float* __restrict__ b_ih,
                            const float* __restrict__ b_hh, const float* __restrict__ w_hh,
                            const float* __restrict__ wsrc, const float* __restrict__ wdst,
                            const float* __restrict__ out_w, const float* __restrict__ out_b,
                            const float* __restrict__ gat_b,
                            float* __restrict__ Wc, float* __restrict__ bc,
                            float* __restrict__ wsT, float* __restrict__ wdT,
                            float* __restrict__ wso, float* __restrict__ cy,
                            unsigned char* __restrict__ whh8) {
    int id = blockIdx.x * 256 + threadIdx.x;
    if (id < P_O0) {
        int g = id >> 6, i = id & 63;
        float s = 0.f;
        for (int k = 0; k < HDIM; k++) s += pre_w[i * HDIM + k] * w_ih[g * HDIM + k];
        int gate = g >> 7;
        Wc[id] = s * ((gate == 2) ? -2.f * LOG2E : -LOG2E);
    } else if (id < P_O1) {
        int g = id - P_O0;
        float s = b_ih[g] + b_hh[g];
        for (int k = 0; k < HDIM; k++) s += pre_b[k] * w_ih[g * HDIM + k];
        int gate = g >> 7;
        bc[g] = s * ((gate == 2) ? -2.f * LOG2E : -LOG2E);
    } else if (id < P_O2) {
        int c = id - P_O1;
        int co = c >> 7, k = c & 127;
        wsT[c] = wsrc[k * HDIM + co];
    } else if (id < P_O3) {
        int c = id - P_O2;
        int co = c >> 7, k = c & 127;
        wdT[c] = wdst[k * HDIM + co];
    } else if (id < P_O4) {
        int hi = id - P_O3;
        float s = 0.f;
        for (int ho = 0; ho < HDIM; ho++) s += wsrc[hi * HDIM + ho] * out_w[ho];
        wso[hi] = s;
    } else if (id == P_O4) {
        float s = out_b[0];
        for (int h = 0; h < HDIM; h++) s += gat_b[h] * out_w[h];
        cy[0] = s;
    } else if (id < P_O6) {
        int c = id - P_O5;
        int gate = c >> 14;                      // row = c>>7, gate = row>>7
        float v = w_hh[c] * ((gate == 2) ? -2.f * LOG2E : -LOG2E);
        int pk = __builtin_amdgcn_cvt_pk_fp8_f32(v, v, 0, false);
        whh8[c] = (unsigned char)(pk & 0xff);
    }
}

// ---------------- K1: xw[row][h*4+gate] = input[row,:64] . Wc[g,:] + bc[g] ---
// (gate- and log2e-prescaled upstream; gate-interleaved per h -> one uint2/lane)
__global__ __launch_bounds__(512) void xw_kernel(const float* __restrict__ input,
                                                 const float* __restrict__ Wc,
                                                 const float* __restrict__ bc,
                                                 bf16* __restrict__ xw) {
    __shared__ __align__(16) float in_lds[16 * INDIM];   // 4KB: 16 rows
    int tid = threadIdx.x;
    int rowbase = blockIdx.x * 16;
    in_lds[tid]       = input[(size_t)rowbase * INDIM + tid];
    in_lds[tid + 512] = input[(size_t)rowbase * INDIM + tid + 512];
    __syncthreads();
    int g = tid;
    int gate = g >> 7, hh = g & 127;
    float4 w[16];
    const float4* wr = reinterpret_cast<const float4*>(Wc + g * INDIM);
#pragma unroll
    for (int u = 0; u < 16; u++) w[u] = wr[u];
    float b = bc[g];
    for (int r = 0; r < 16; r++) {
        const float4* hv = reinterpret_cast<const float4*>(in_lds + r * INDIM);
        float a0 = b, a1 = 0.f, a2 = 0.f, a3 = 0.f;
#pragma unroll
        for (int u = 0; u < 16; u++) {
            float4 h4 = hv[u]; float4 wv = w[u];
            a0 = fmaf(h4.x, wv.x, a0); a1 = fmaf(h4.y, wv.y, a1);
            a2 = fmaf(h4.z, wv.z, a2); a3 = fmaf(h4.w, wv.w, a3);
        }
        xw[(size_t)(rowbase + r) * G4 + hh * 4 + gate] = __float2bfloat16((a0 + a1) + (a2 + a3));
    }
}

// ---------------- K2: sequential LSTM scan, 4 chains/block, 2 blocks ---------
// MX fp8 K=128 MFMA: one mfma_scale_f32_16x16x128_f8f6f4 per gate tile per
// step (4/wave). Chain stride 144 B: (36q+8kg) mod 32 gives exactly 2-way
// bank aliasing on the two b128 reads = free (m136). Gate i,f,g,o in-lane;
// 1 barrier/step; vmcnt never drained in-loop; bare v_exp_f32 transcendentals.
__global__ __launch_bounds__(512, 1) void lstm_kernel(const bf16* __restrict__ xw,
                                                      const unsigned char* __restrict__ whh8,
                                                      const float* __restrict__ hidden0,
                                                      const float* __restrict__ cell0,
                                                      float* __restrict__ outs,
                                                      float* __restrict__ dout) {
    // h matrix [4 chains][128] fp8, chain stride 144 B (16B-aligned)
    __shared__ __align__(16) char hbuf0[4 * 144];
    __shared__ __align__(16) char hbuf1[4 * 144];
    const int tid  = threadIdx.x;
    const int w    = tid >> 6;
    const int lane = tid & 63;
    const int kg   = lane >> 4;        // 0..3 (k-group of 32; also C-row block)
    const int lr   = lane & 15;        // A-row in tile; C col
    const int q    = lr & 3;           // chain within block
    const int d    = lr >> 2;          // which C reg this lane consumes
    const int qg   = blockIdx.x * 4 + q;          // global chain (t)
    const int hb   = 16 * w + kg * 4 + d;         // this lane's h index

    // Persistent A fragments (fp8): gate G rows G*128+16w+lr, k-bytes kg*32..+32
    i32x8 afr[4];
#pragma unroll
    for (int G = 0; G < 4; G++) {
        const unsigned char* rowp = whh8 + (size_t)(G * 128 + 16 * w + lr) * HDIM + kg * 32;
        afr[G] = *reinterpret_cast<const i32x8*>(rowp);
    }

    const int roff = q * 144 + kg * 32;   // B-frag read base (32 contiguous bytes)
    const int woff = q * 144 + hb;        // h write (1 byte)
    const int sc   = 0x7f7f7f7f;          // e8m0 scale 1.0 in every byte

    // init states
    float cv = cell0[qg * HDIM + hb];
    float hv = hidden0[qg * HDIM + hb];
    {
        int pk = __builtin_amdgcn_cvt_pk_fp8_f32(hv, hv, 0, false);
        *reinterpret_cast<unsigned char*>(hbuf0 + woff) = (unsigned char)(pk & 0xff);
    }

    // xw: row (n*8+qg), this h's 4 gates = 8 bytes -> uint2 idx row*128 + hb
    const uint2* xq = reinterpret_cast<const uint2*>(xw) + qg * 128 + hb;
    float* outp = outs + qg * HDIM + hb;

    uint2 xb[8];
#pragma unroll
    for (int i = 0; i < 8; i++) xb[i] = xq[i * 1024];
    __syncthreads();

#define STEPX(NIDX, RB, WB, XQ)                                                      \
    do {                                                                             \
        i32x8 bfr = *reinterpret_cast<const i32x8*>(RB + roff);                      \
        f32x4 z = {0.f, 0.f, 0.f, 0.f};                                              \
        f32x4 acc0 = __builtin_amdgcn_mfma_scale_f32_16x16x128_f8f6f4(               \
            afr[0], bfr, z, 0, 0, 0, sc, 0, sc);                                     \
        f32x4 acc1 = __builtin_amdgcn_mfma_scale_f32_16x16x128_f8f6f4(               \
            afr[1], bfr, z, 0, 0, 0, sc, 0, sc);                                     \
        f32x4 acc2 = __builtin_amdgcn_mfma_scale_f32_16x16x128_f8f6f4(               \
            afr[2], bfr, z, 0, 0, 0, sc, 0, sc);                                     \
        f32x4 acc3 = __builtin_amdgcn_mfma_scale_f32_16x16x128_f8f6f4(               \
            afr[3], bfr, z, 0, 0, 0, sc, 0, sc);                                     \
        float s0 = (d & 2) ? ((d & 1) ? acc0[3] : acc0[2])                           \
                           : ((d & 1) ? acc0[1] : acc0[0]);                          \
        float s1 = (d & 2) ? ((d & 1) ? acc1[3] : acc1[2])                           \
                           : ((d & 1) ? acc1[1] : acc1[0]);                          \
        float s2 = (d & 2) ? ((d & 1) ? acc2[3] : acc2[2])                           \
                           : ((d & 1) ? acc2[1] : acc2[0]);                          \
        float s3 = (d & 2) ? ((d & 1) ? acc3[3] : acc3[2])                           \
                           : ((d & 1) ? acc3[1] : acc3[0]);                          \
        float gi = s0 + asfloat_u((XQ).x << 16);                                     \
        float gf = s1 + asfloat_u((XQ).x & 0xffff0000u);                             \
        float gg = s2 + asfloat_u((XQ).y << 16);                                     \
        float go = s3 + asfloat_u((XQ).y & 0xffff0000u);                             \
        float A = fexp2(gi), C = fexp2(gf), B = fexp2(gg);                           \
        float p = 1.f + A, r = 1.f + B, s = 1.f + C;                                 \
        float pr = p * r;                                                            \
        float num = fmaf(cv, pr, (2.f - r) * s);                                     \
        cv = num * __builtin_amdgcn_rcpf(pr * s);                                    \
        float O = fexp2(go), F = fexp2(cv * (-2.f * LOG2E));                         \
        float po = 1.f + O, rf = 1.f + F;                                            \
        hv = (2.f - rf) * __builtin_amdgcn_rcpf(po * rf);                            \
        int pk = __builtin_amdgcn_cvt_pk_fp8_f32(hv, hv, 0, false);                  \
        *reinterpret_cast<unsigned char*>(WB + woff) = (unsigned char)(pk & 0xff);   \
        outp[(NIDX) * 1024] = hv;                                                    \
        asm volatile("s_waitcnt lgkmcnt(0)" ::: "memory");                           \
        __builtin_amdgcn_s_barrier();                                                \
        __builtin_amdgcn_sched_barrier(0);                                           \
    } while (0)

    for (int n = 0; n < N_NODES; n += 8) {
#pragma unroll
        for (int i = 0; i < 8; i++) {
            if (i & 1) STEPX(n + i, hbuf1, hbuf0, xb[i]);
            else       STEPX(n + i, hbuf0, hbuf1, xb[i]);
            // reload 8 steps ahead; tail reads land in outs region (in-bounds,
            // never consumed) so no conditionals needed
            xb[i] = xq[(n + i + 8) * 1024];
        }
    }
#undef STEPX

    dout[NROWS + qg * HDIM + hb] = hv;                        // hT
    dout[NROWS + T_STEPS * HDIM + qg * HDIM + hb] = cv;       // cT
}

// ---------------- K3: fs = outs@wsrc, fd = outs@wdst (bf16 out) --------------
__global__ __launch_bounds__(256) void fsfd_kernel(const float* __restrict__ outs,
                                                   const float* __restrict__ wsT,
                                                   const float* __restrict__ wdT,
                                                   bf16* __restrict__ fs,
                                                   bf16* __restrict__ fd) {
    __shared__ __align__(16) float rows[32 * HDIM];    // 16KB: 32 rows
    int tid = threadIdx.x;
    size_t base = (size_t)blockIdx.x * 32 * HDIM;
#pragma unroll
    for (int j = 0; j < 16; j++) rows[tid + j * 256] = outs[base + tid + j * 256];
    __syncthreads();
    int c = tid;
    const float4* wT = reinterpret_cast<const float4*>(
        (c < HDIM) ? (wsT + c * HDIM) : (wdT + (c - HDIM) * HDIM));
    float4 w[32];
#pragma unroll
    for (int u = 0; u < 32; u++) w[u] = wT[u];
    bf16* dst = (c < HDIM) ? (fs + base + c) : (fd + base + (c - HDIM));
    for (int r = 0; r < 32; r++) {
        const float4* hv = reinterpret_cast<const float4*>(rows + r * HDIM);
        float a0 = 0.f, a1 = 0.f, a2 = 0.f, a3 = 0.f;
#pragma unroll
        for (int u = 0; u < 32; u++) {
            float4 h4 = hv[u]; float4 wv = w[u];
            a0 = fmaf(h4.x, wv.x, a0); a1 = fmaf(h4.y, wv.y, a1);
            a2 = fmaf(h4.z, wv.z, a2); a3 = fmaf(h4.w, wv.w, a3);
        }
        dst[(size_t)r * HDIM] = __float2bfloat16((a0 + a1) + (a2 + a3));
    }
}

// ---------------- K3b: fso[row] = outs[row,:] . wso --------------------------
__global__ __launch_bounds__(256) void fso_kernel(const float* __restrict__ outs,
                                                  const float* __restrict__ wso,
                                                  float* __restrict__ fso) {
    int tid = threadIdx.x;
    int l = tid & 63;
    int row = blockIdx.x * 4 + (tid >> 6);
    float v = outs[(size_t)row * HDIM + l] * wso[l]
            + outs[(size_t)row * HDIM + 64 + l] * wso[64 + l];
#pragma unroll
    for (int m = 32; m >= 1; m >>= 1) v += __shfl_xor(v, m, 64);
    if (l == 0) fso[row] = v;
}

// ---------------- K4: per-edge softmax numerators ----------------------------
__global__ __launch_bounds__(256) void edge_kernel(const int* __restrict__ esrc,
                                                   const int* __restrict__ edst,
                                                   const bf16* __restrict__ fs,
                                                   const bf16* __restrict__ fd,
                                                   const float* __restrict__ attn,
                                                   const float* __restrict__ fso,
                                                   float* __restrict__ denom,
                                                   float* __restrict__ ynum, int nE) {
    int tid = threadIdx.x;
    int l = tid & 63;
    int e = blockIdx.x * 4 + (tid >> 6);
    if (e >= nE) return;
    int s = esrc[e], d = edst[e];
    float at1 = attn[l], at2 = attn[64 + l];
    const bf16* fsr = fs + (size_t)s * (T_STEPS * HDIM);
    const bf16* fdr = fd + (size_t)d * (T_STEPS * HDIM);
#pragma unroll
    for (int t = 0; t < T_STEPS; t++) {
        float x1 = __bfloat162float(fsr[t * HDIM + l]) + __bfloat162float(fdr[t * HDIM + l]);
        float x2 = __bfloat162float(fsr[t * HDIM + 64 + l]) + __bfloat162float(fdr[t * HDIM + 64 + l]);
        x1 = fmaxf(x1, 0.f) + 0.2f * fminf(x1, 0.f);
        x2 = fmaxf(x2, 0.f) + 0.2f * fminf(x2, 0.f);
        float v = x1 * at1 + x2 * at2;
#pragma unroll
        for (int m = 32; m >= 1; m >>= 1) v += __shfl_xor(v, m, 64);
        if (l == 0) {
            float a = __expf(v);
            atomicAdd(&denom[d * T_STEPS + t], a);
            atomicAdd(&ynum[d * T_STEPS + t], a * fso[s * T_STEPS + t]);
        }
    }
}

// ---------------- K5: finalize y ---------------------------------------------
__global__ void final_kernel(const float* __restrict__ ynum, const float* __restrict__ denom,
                             const float* __restrict__ cy, float* __restrict__ dout) {
    int i = blockIdx.x * 256 + threadIdx.x;
    if (i < NROWS) dout[i] = ynum[i] / denom[i] + cy[0];
}

extern "C" void kernel_launch(void* const* d_in, const int* in_sizes, int n_in,
                              void* d_out, int out_size, void* d_ws, size_t ws_size,
                              hipStream_t stream) {
    const float* input  = (const float*)d_in[0];
    const float* hidden = (const float*)d_in[1];
    const float* cell   = (const float*)d_in[2];
    const float* pre_w  = (const float*)d_in[3];
    const float* pre_b  = (const float*)d_in[4];
    const float* w_ih   = (const float*)d_in[5];
    const float* w_hh   = (const float*)d_in[6];
    const float* b_ih   = (const float*)d_in[7];
    const float* b_hh   = (const float*)d_in[8];
    const float* wsrc   = (const float*)d_in[9];
    const float* wdst   = (const float*)d_in[10];
    const float* attn   = (const float*)d_in[11];
    const float* gatb   = (const float*)d_in[12];
    const float* outw   = (const float*)d_in[13];
    const float* outb   = (const float*)d_in[14];
    const int*   esrc   = (const int*)d_in[15];
    const int*   edst   = (const int*)d_in[16];
    int nE = in_sizes[15];
    float* dout = (float*)d_out;
    char* ws = (char*)d_ws;

    // workspace layout (bytes, 256-aligned)
    const size_t o_xw    = 0;                 // 32768*512*2  = 33,554,432
    const size_t o_outs  = 33554432;          // 32768*128*4  = 16,777,216
    const size_t o_fs    = 50331648;          // 32768*128*2  =  8,388,608
    const size_t o_fd    = 58720256;          //               8,388,608
    const size_t o_fso   = 67108864;          // 32768*4      =    131,072
    const size_t o_denom = 67239936;          //    131,072
    const size_t o_ynum  = 67371008;          //    131,072
    const size_t o_wc    = 67502080;          //    131,072
    const size_t o_bc    = 67633152;          //      2,048
    const size_t o_wsT   = 67635200;          //     65,536
    const size_t o_wdT   = 67700736;          //     65,536
    const size_t o_wso   = 67766272;          //        512
    const size_t o_cy    = 67766784;          //          4
    const size_t o_whh8  = o_fs;              // fp8 w_hh overlaps fs (disjoint in time)

    bf16*  xw    = (bf16*)(ws + o_xw);
    float* outs  = (float*)(ws + o_outs);
    bf16*  fs    = (bf16*)(ws + o_fs);
    bf16*  fd    = (bf16*)(ws + o_fd);
    float* fso   = (float*)(ws + o_fso);
    float* denom = (float*)(ws + o_denom);
    float* ynum  = (float*)(ws + o_ynum);
    float* Wc    = (float*)(ws + o_wc);
    float* bc    = (float*)(ws + o_bc);
    float* wsT   = (float*)(ws + o_wsT);
    float* wdT   = (float*)(ws + o_wdT);
    float* wso   = (float*)(ws + o_wso);
    float* cy    = (float*)(ws + o_cy);
    unsigned char* whh8 = (unsigned char*)(ws + o_whh8);

    prep_kernel<<<515, 256, 0, stream>>>(pre_w, pre_b, w_ih, b_ih, b_hh, w_hh, wsrc, wdst,
                                         outw, outb, gatb, Wc, bc, wsT, wdT, wso, cy, whh8);
    xw_kernel<<<2048, 512, 0, stream>>>(input, Wc, bc, xw);
    lstm_kernel<<<2, 512, 0, stream>>>(xw, whh8, hidden, cell, outs, dout);
    fsfd_kernel<<<1024, 256, 0, stream>>>(outs, wsT, wdT, fs, fd);
    fso_kernel<<<8192, 256, 0, stream>>>(outs, wso, fso);
    hipMemsetAsync(ws + o_denom, 0, 262144, stream);   // denom + ynum
    edge_kernel<<<(nE + 3) / 4, 256, 0, stream>>>(esrc, edst, fs, fd, attn, fso,
                                                  denom, ynum, nE);
    final_kernel<<<128, 256, 0, stream>>>(ynum, denom, cy, dout);
}

// Round 10
// 1685.491 us; speedup vs baseline: 3.0157x; 1.0043x over previous
//
#include <hip/hip_runtime.h>
#include <hip/hip_bf16.h>

#define N_NODES 4096
#define T_STEPS 8
#define INDIM   64
#define HDIM    128
#define G4      512                    // 4*H
#define NROWS   (N_NODES * T_STEPS)    // 32768
#define LOG2E   1.4426950408889634f

typedef __hip_bfloat16 bf16;
typedef __attribute__((ext_vector_type(8))) short bf16x8;
typedef __attribute__((ext_vector_type(4))) float f32x4;
typedef __attribute__((ext_vector_type(8))) int   i32x8;

__device__ __forceinline__ float asfloat_u(unsigned int u) {
    union { unsigned int i; float f; } v; v.i = u; return v.f;
}
// bare hardware exp2 (1 instr; OCML exp2f carries fixup code without fast-math)
__device__ __forceinline__ float fexp2(float x) {
    float r; asm("v_exp_f32 %0, %1" : "=v"(r) : "v"(x)); return r;
}

// ---------------- K0: fold weights + fp8 conversions -------------------------
// Gate pre-scaling: gates i,f,o rows scaled by -log2e, gate g rows by -2*log2e
// (device exp chains are bare v_exp_f32 = 2^x). attn2 = attn*log2e (edge exp).
#define P_O0 32768
#define P_O1 (P_O0 + 512)
#define P_O2 (P_O1 + 16384)
#define P_O3 (P_O2 + 16384)
#define P_O4 (P_O3 + 128)
#define P_O5 (P_O4 + 1)
#define P_O6 (P_O5 + 65536)
#define P_O7 (P_O6 + 128)
__global__ void prep_kernel(const float* __restrict__ pre_w, const float* __restrict__ pre_b,
                            const float* __restrict__ w_ih, const float* __restrict__ b_ih,
                            const float* __restrict__ b_hh, const float* __restrict__ w_hh,
                            const float* __restrict__ wsrc, const float* __restrict__ wdst,
                            const float* __restrict__ out_w, const float* __restrict__ out_b,
                            const float* __restrict__ gat_b, const float* __restrict__ attn,
                            float* __restrict__ Wc, float* __restrict__ bc,
                            float* __restrict__ wsT, float* __restrict__ wdT,
                            float* __restrict__ wso, float* __restrict__ cy,
                            unsigned char* __restrict__ whh8, float* __restrict__ attn2) {
    int id = blockIdx.x * 256 + threadIdx.x;
    if (id < P_O0) {
        int g = id >> 6, i = id & 63;
        float s = 0.f;
        for (int k = 0; k < HDIM; k++) s += pre_w[i * HDIM + k] * w_ih[g * HDIM + k];
        int gate = g >> 7;
        Wc[id] = s * ((gate == 2) ? -2.f * LOG2E : -LOG2E);
    } else if (id < P_O1) {
        int g = id - P_O0;
        float s = b_ih[g] + b_hh[g];
        for (int k = 0; k < HDIM; k++) s += pre_b[k] * w_ih[g * HDIM + k];
        int gate = g >> 7;
        bc[g] = s * ((gate == 2) ? -2.f * LOG2E : -LOG2E);
    } else if (id < P_O2) {
        int c = id - P_O1;
        int co = c >> 7, k = c & 127;
        wsT[c] = wsrc[k * HDIM + co];
    } else if (id < P_O3) {
        int c = id - P_O2;
        int co = c >> 7, k = c & 127;
        wdT[c] = wdst[k * HDIM + co];
    } else if (id < P_O4) {
        int hi = id - P_O3;
        float s = 0.f;
        for (int ho = 0; ho < HDIM; ho++) s += wsrc[hi * HDIM + ho] * out_w[ho];
        wso[hi] = s;
    } else if (id == P_O4) {
        float s = out_b[0];
        for (int h = 0; h < HDIM; h++) s += gat_b[h] * out_w[h];
        cy[0] = s;
    } else if (id < P_O6) {
        int c = id - P_O5;
        int gate = c >> 14;                      // row = c>>7, gate = row>>7
        float v = w_hh[c] * ((gate == 2) ? -2.f * LOG2E : -LOG2E);
        int pk = __builtin_amdgcn_cvt_pk_fp8_f32(v, v, 0, false);
        whh8[c] = (unsigned char)(pk & 0xff);
    } else if (id < P_O7) {
        int c = id - P_O6;
        attn2[c] = attn[c] * LOG2E;
    }
}

// ---------------- K1: xw[row][h*4+gate] = input[row,:64] . Wc[g,:] + bc[g] ---
__global__ __launch_bounds__(512) void xw_kernel(const float* __restrict__ input,
                                                 const float* __restrict__ Wc,
                                                 const float* __restrict__ bc,
                                                 bf16* __restrict__ xw) {
    __shared__ __align__(16) float in_lds[16 * INDIM];   // 4KB: 16 rows
    int tid = threadIdx.x;
    int rowbase = blockIdx.x * 16;
    in_lds[tid]       = input[(size_t)rowbase * INDIM + tid];
    in_lds[tid + 512] = input[(size_t)rowbase * INDIM + tid + 512];
    __syncthreads();
    int g = tid;
    int gate = g >> 7, hh = g & 127;
    float4 w[16];
    const float4* wr = reinterpret_cast<const float4*>(Wc + g * INDIM);
#pragma unroll
    for (int u = 0; u < 16; u++) w[u] = wr[u];
    float b = bc[g];
    for (int r = 0; r < 16; r++) {
        const float4* hv = reinterpret_cast<const float4*>(in_lds + r * INDIM);
        float a0 = b, a1 = 0.f, a2 = 0.f, a3 = 0.f;
#pragma unroll
        for (int u = 0; u < 16; u++) {
            float4 h4 = hv[u]; float4 wv = w[u];
            a0 = fmaf(h4.x, wv.x, a0); a1 = fmaf(h4.y, wv.y, a1);
            a2 = fmaf(h4.z, wv.z, a2); a3 = fmaf(h4.w, wv.w, a3);
        }
        xw[(size_t)(rowbase + r) * G4 + hh * 4 + gate] = __float2bfloat16((a0 + a1) + (a2 + a3));
    }
}

// ---------------- sort edges by dst: hist -> scan -> scatter -----------------
__global__ void hist_kernel(const int* __restrict__ edst, int nE, int* __restrict__ cnt) {
    int i = blockIdx.x * 256 + threadIdx.x;
    if (i < nE) atomicAdd(&cnt[edst[i]], 1);
}

__global__ __launch_bounds__(512) void scan_kernel(const int* __restrict__ cnt,
                                                   int* __restrict__ rowptr) {
    __shared__ int part[512];
    int t = threadIdx.x, base = t * 8;
    int loc[8]; int s = 0;
#pragma unroll
    for (int j = 0; j < 8; j++) { loc[j] = s; s += cnt[base + j]; }
    part[t] = s;
    __syncthreads();
    for (int off = 1; off < 512; off <<= 1) {
        int v = (t >= off) ? part[t - off] : 0;
        __syncthreads();
        part[t] += v;
        __syncthreads();
    }
    int pre = part[t] - s;
#pragma unroll
    for (int j = 0; j < 8; j++) rowptr[base + j] = pre + loc[j];
    if (t == 511) rowptr[4096] = part[511];
}

__global__ void scatter_kernel(const int* __restrict__ esrc, const int* __restrict__ edst,
                               int nE, const int* __restrict__ rowptr,
                               int* __restrict__ cnt2, int* __restrict__ ssrc) {
    int i = blockIdx.x * 256 + threadIdx.x;
    if (i < nE) {
        int d = edst[i];
        int pos = rowptr[d] + atomicAdd(&cnt2[d], 1);
        ssrc[pos] = esrc[i];
    }
}

// ---------------- K2: sequential LSTM scan, 4 chains/block, 2 blocks ---------
__global__ __launch_bounds__(512, 1) void lstm_kernel(const bf16* __restrict__ xw,
                                                      const unsigned char* __restrict__ whh8,
                                                      const float* __restrict__ hidden0,
                                                      const float* __restrict__ cell0,
                                                      float* __restrict__ outs,
                                                      float* __restrict__ dout) {
    __shared__ __align__(16) char hbuf0[4 * 144];
    __shared__ __align__(16) char hbuf1[4 * 144];
    const int tid  = threadIdx.x;
    const int w    = tid >> 6;
    const int lane = tid & 63;
    const int kg   = lane >> 4;
    const int lr   = lane & 15;
    const int q    = lr & 3;
    const int d    = lr >> 2;
    const int qg   = blockIdx.x * 4 + q;
    const int hb   = 16 * w + kg * 4 + d;

    i32x8 afr[4];
#pragma unroll
    for (int G = 0; G < 4; G++) {
        const unsigned char* rowp = whh8 + (size_t)(G * 128 + 16 * w + lr) * HDIM + kg * 32;
        afr[G] = *reinterpret_cast<const i32x8*>(rowp);
    }

    const int roff = q * 144 + kg * 32;
    const int woff = q * 144 + hb;
    const int sc   = 0x7f7f7f7f;

    float cv = cell0[qg * HDIM + hb];
    float hv = hidden0[qg * HDIM + hb];
    {
        int pk = __builtin_amdgcn_cvt_pk_fp8_f32(hv, hv, 0, false);
        *reinterpret_cast<unsigned char*>(hbuf0 + woff) = (unsigned char)(pk & 0xff);
    }

    const uint2* xq = reinterpret_cast<const uint2*>(xw) + qg * 128 + hb;
    float* outp = outs + qg * HDIM + hb;

    uint2 xb[8];
#pragma unroll
    for (int i = 0; i < 8; i++) xb[i] = xq[i * 1024];
    __syncthreads();

#define STEPX(NIDX, RB, WB, XQ)                                                      \
    do {                                                                             \
        i32x8 bfr = *reinterpret_cast<const i32x8*>(RB + roff);                      \
        f32x4 z = {0.f, 0.f, 0.f, 0.f};                                              \
        f32x4 acc0 = __builtin_amdgcn_mfma_scale_f32_16x16x128_f8f6f4(               \
            afr[0], bfr, z, 0, 0, 0, sc, 0, sc);                                     \
        f32x4 acc1 = __builtin_amdgcn_mfma_scale_f32_16x16x128_f8f6f4(               \
            afr[1], bfr, z, 0, 0, 0, sc, 0, sc);                                     \
        f32x4 acc2 = __builtin_amdgcn_mfma_scale_f32_16x16x128_f8f6f4(               \
            afr[2], bfr, z, 0, 0, 0, sc, 0, sc);                                     \
        f32x4 acc3 = __builtin_amdgcn_mfma_scale_f32_16x16x128_f8f6f4(               \
            afr[3], bfr, z, 0, 0, 0, sc, 0, sc);                                     \
        float s0 = (d & 2) ? ((d & 1) ? acc0[3] : acc0[2])                           \
                           : ((d & 1) ? acc0[1] : acc0[0]);                          \
        float s1 = (d & 2) ? ((d & 1) ? acc1[3] : acc1[2])                           \
                           : ((d & 1) ? acc1[1] : acc1[0]);                          \
        float s2 = (d & 2) ? ((d & 1) ? acc2[3] : acc2[2])                           \
                           : ((d & 1) ? acc2[1] : acc2[0]);                          \
        float s3 = (d & 2) ? ((d & 1) ? acc3[3] : acc3[2])                           \
                           : ((d & 1) ? acc3[1] : acc3[0]);                          \
        float gi = s0 + asfloat_u((XQ).x << 16);                                     \
        float gf = s1 + asfloat_u((XQ).x & 0xffff0000u);                             \
        float gg = s2 + asfloat_u((XQ).y << 16);                                     \
        float go = s3 + asfloat_u((XQ).y & 0xffff0000u);                             \
        float A = fexp2(gi), C = fexp2(gf), B = fexp2(gg);                           \
        float p = 1.f + A, r = 1.f + B, s = 1.f + C;                                 \
        float pr = p * r;                                                            \
        float num = fmaf(cv, pr, (2.f - r) * s);                                     \
        cv = num * __builtin_amdgcn_rcpf(pr * s);                                    \
        float O = fexp2(go), F = fexp2(cv * (-2.f * LOG2E));                         \
        float po = 1.f + O, rf = 1.f + F;                                            \
        hv = (2.f - rf) * __builtin_amdgcn_rcpf(po * rf);                            \
        int pk = __builtin_amdgcn_cvt_pk_fp8_f32(hv, hv, 0, false);                  \
        *reinterpret_cast<unsigned char*>(WB + woff) = (unsigned char)(pk & 0xff);   \
        outp[(NIDX) * 1024] = hv;                                                    \
        asm volatile("s_waitcnt lgkmcnt(0)" ::: "memory");                           \
        __builtin_amdgcn_s_barrier();                                                \
        __builtin_amdgcn_sched_barrier(0);                                           \
    } while (0)

    for (int n = 0; n < N_NODES; n += 8) {
#pragma unroll
        for (int i = 0; i < 8; i++) {
            if (i & 1) STEPX(n + i, hbuf1, hbuf0, xb[i]);
            else       STEPX(n + i, hbuf0, hbuf1, xb[i]);
            xb[i] = xq[(n + i + 8) * 1024];
        }
    }
#undef STEPX

    dout[NROWS + qg * HDIM + hb] = hv;                        // hT
    dout[NROWS + T_STEPS * HDIM + qg * HDIM + hb] = cv;       // cT
}

// ---------------- K3: fs/fd GEMV + fused fso ---------------------------------
__global__ __launch_bounds__(256) void fsfd_kernel(const float* __restrict__ outs,
                                                   const float* __restrict__ wsT,
                                                   const float* __restrict__ wdT,
                                                   const float* __restrict__ wso,
                                                   bf16* __restrict__ fs,
                                                   bf16* __restrict__ fd,
                                                   float* __restrict__ fso) {
    __shared__ __align__(16) float rows[32 * HDIM];    // 16KB: 32 rows
    int tid = threadIdx.x;
    size_t base = (size_t)blockIdx.x * 32 * HDIM;
#pragma unroll
    for (int j = 0; j < 16; j++) rows[tid + j * 256] = outs[base + tid + j * 256];
    __syncthreads();
    int c = tid;
    const float4* wT = reinterpret_cast<const float4*>(
        (c < HDIM) ? (wsT + c * HDIM) : (wdT + (c - HDIM) * HDIM));
    float4 w[32];
#pragma unroll
    for (int u = 0; u < 32; u++) w[u] = wT[u];
    bf16* dst = (c < HDIM) ? (fs + base + c) : (fd + base + (c - HDIM));
    for (int r = 0; r < 32; r++) {
        const float4* hv = reinterpret_cast<const float4*>(rows + r * HDIM);
        float a0 = 0.f, a1 = 0.f, a2 = 0.f, a3 = 0.f;
#pragma unroll
        for (int u = 0; u < 32; u++) {
            float4 h4 = hv[u]; float4 wv = w[u];
            a0 = fmaf(h4.x, wv.x, a0); a1 = fmaf(h4.y, wv.y, a1);
            a2 = fmaf(h4.z, wv.z, a2); a3 = fmaf(h4.w, wv.w, a3);
        }
        dst[(size_t)r * HDIM] = __float2bfloat16((a0 + a1) + (a2 + a3));
    }
    // fused fso: row-dot with wso (rotation k' = (k+tid)&127 -> conflict-free)
    if (tid < 32) {
        const float* rp = rows + tid * HDIM;
        float s = 0.f;
        for (int k = 0; k < HDIM; k++) {
            int kk = (k + tid) & 127;
            s += rp[kk] * wso[kk];
        }
        fso[blockIdx.x * 32 + tid] = s;
    }
}

// ---------------- K4: per-dst edge softmax (CSR, no atomics) -----------------
// One wave per dst node. Lane l covers h-pair (2l, 2l+1). fd row dwords live
// in registers; per source edge: vectorized fs dword loads, leaky+dot, butterfly
// reduce (all lanes end with the logit), a=2^v, accumulate den/num in regs.
// Epilogue writes y = num/den + cy directly (final_kernel fused).
__global__ __launch_bounds__(64) void edge_csr_kernel(const int* __restrict__ ssrc,
                                                      const int* __restrict__ rowptr,
                                                      const bf16* __restrict__ fs,
                                                      const bf16* __restrict__ fd,
                                                      const float* __restrict__ attn2,
                                                      const float* __restrict__ fso,
                                                      const float* __restrict__ cy,
                                                      float* __restrict__ dout) {
    int dn = blockIdx.x;
    int l  = threadIdx.x;
    float a0 = attn2[2 * l], a1 = attn2[2 * l + 1];
    const unsigned int* fdp = reinterpret_cast<const unsigned int*>(fd) + (size_t)dn * 512 + l;
    unsigned int fdw[8];
#pragma unroll
    for (int t = 0; t < 8; t++) fdw[t] = fdp[t * 64];
    float den[8], num[8];
#pragma unroll
    for (int t = 0; t < 8; t++) { den[t] = 0.f; num[t] = 0.f; }
    int e0 = rowptr[dn], e1 = rowptr[dn + 1];
    for (int e = e0; e < e1; e++) {
        int s = ssrc[e];
        const unsigned int* fsp = reinterpret_cast<const unsigned int*>(fs) + (size_t)s * 512 + l;
        float4 fsoA = *reinterpret_cast<const float4*>(fso + s * 8);
        float4 fsoB = *reinterpret_cast<const float4*>(fso + s * 8 + 4);
        float fsov[8] = {fsoA.x, fsoA.y, fsoA.z, fsoA.w, fsoB.x, fsoB.y, fsoB.z, fsoB.w};
#pragma unroll
        for (int t = 0; t < 8; t++) {
            unsigned int uf = fsp[t * 64];
            float x1 = asfloat_u(uf << 16) + asfloat_u(fdw[t] << 16);
            float x2 = asfloat_u(uf & 0xffff0000u) + asfloat_u(fdw[t] & 0xffff0000u);
            x1 = fmaxf(x1, 0.f) + 0.2f * fminf(x1, 0.f);
            x2 = fmaxf(x2, 0.f) + 0.2f * fminf(x2, 0.f);
            float v = x1 * a0 + x2 * a1;
#pragma unroll
            for (int m = 32; m >= 1; m >>= 1) v += __shfl_xor(v, m, 64);
            float a = fexp2(v);
            den[t] += a;
            num[t] = fmaf(a, fsov[t], num[t]);
        }
    }
    if (l == 0) {
        float cyv = cy[0];
        float4 y0, y1;
        y0.x = num[0] * __builtin_amdgcn_rcpf(den[0]) + cyv;
        y0.y = num[1] * __builtin_amdgcn_rcpf(den[1]) + cyv;
        y0.z = num[2] * __builtin_amdgcn_rcpf(den[2]) + cyv;
        y0.w = num[3] * __builtin_amdgcn_rcpf(den[3]) + cyv;
        y1.x = num[4] * __builtin_amdgcn_rcpf(den[4]) + cyv;
        y1.y = num[5] * __builtin_amdgcn_rcpf(den[5]) + cyv;
        y1.z = num[6] * __builtin_amdgcn_rcpf(den[6]) + cyv;
        y1.w = num[7] * __builtin_amdgcn_rcpf(den[7]) + cyv;
        *reinterpret_cast<float4*>(dout + dn * 8)     = y0;
        *reinterpret_cast<float4*>(dout + dn * 8 + 4) = y1;
    }
}

extern "C" void kernel_launch(void* const* d_in, const int* in_sizes, int n_in,
                              void* d_out, int out_size, void* d_ws, size_t ws_size,
                              hipStream_t stream) {
    const float* input  = (const float*)d_in[0];
    const float* hidden = (const float*)d_in[1];
    const float* cell   = (const float*)d_in[2];
    const float* pre_w  = (const float*)d_in[3];
    const float* pre_b  = (const float*)d_in[4];
    const float* w_ih   = (const float*)d_in[5];
    const float* w_hh   = (const float*)d_in[6];
    const float* b_ih   = (const float*)d_in[7];
    const float* b_hh   = (const float*)d_in[8];
    const float* wsrc   = (const float*)d_in[9];
    const float* wdst   = (const float*)d_in[10];
    const float* attn   = (const float*)d_in[11];
    const float* gatb   = (const float*)d_in[12];
    const float* outw   = (const float*)d_in[13];
    const float* outb   = (const float*)d_in[14];
    const int*   esrc   = (const int*)d_in[15];
    const int*   edst   = (const int*)d_in[16];
    int nE = in_sizes[15];
    float* dout = (float*)d_out;
    char* ws = (char*)d_ws;

    // workspace layout (bytes, 256-aligned)
    const size_t o_xw    = 0;                 // 32768*512*2  = 33,554,432
    const size_t o_outs  = 33554432;          // 32768*128*4  = 16,777,216
    const size_t o_fs    = 50331648;          //  8,388,608
    const size_t o_fd    = 58720256;          //  8,388,608
    const size_t o_fso   = 67108864;          //    131,072
    const size_t o_cnt   = 67239936;          //     16,384   (old denom slot)
    const size_t o_cnt2  = 67256320;          //     16,384
    const size_t o_rowptr= 67272704;          //     16,640
    const size_t o_ssrc  = 67289344;          //    278,528 -> ends 67,567,872
                                              //    (overlaps Wc/bc: dead after xw)
    const size_t o_wc    = 67502080;          //    131,072  (dead after xw_kernel)
    const size_t o_bc    = 67633152;          //      2,048
    const size_t o_wsT   = 67635200;          //     65,536
    const size_t o_wdT   = 67700736;          //     65,536
    const size_t o_wso   = 67766272;          //        512
    const size_t o_cy    = 67766784;          //        256 (4 used)
    const size_t o_attn2 = 67767040;          //        512
    const size_t o_whh8  = o_fs;              // fp8 w_hh overlaps fs (disjoint in time)

    bf16*  xw    = (bf16*)(ws + o_xw);
    float* outs  = (float*)(ws + o_outs);
    bf16*  fs    = (bf16*)(ws + o_fs);
    bf16*  fd    = (bf16*)(ws + o_fd);
    float* fso   = (float*)(ws + o_fso);
    int*   cnt   = (int*)(ws + o_cnt);
    int*   cnt2  = (int*)(ws + o_cnt2);
    int*   rowptr= (int*)(ws + o_rowptr);
    int*   ssrc  = (int*)(ws + o_ssrc);
    float* Wc    = (float*)(ws + o_wc);
    float* bc    = (float*)(ws + o_bc);
    float* wsT   = (float*)(ws + o_wsT);
    float* wdT   = (float*)(ws + o_wdT);
    float* wso   = (float*)(ws + o_wso);
    float* cy    = (float*)(ws + o_cy);
    float* attn2 = (float*)(ws + o_attn2);
    unsigned char* whh8 = (unsigned char*)(ws + o_whh8);

    prep_kernel<<<516, 256, 0, stream>>>(pre_w, pre_b, w_ih, b_ih, b_hh, w_hh, wsrc, wdst,
                                         outw, outb, gatb, attn,
                                         Wc, bc, wsT, wdT, wso, cy, whh8, attn2);
    xw_kernel<<<2048, 512, 0, stream>>>(input, Wc, bc, xw);
    // edge sort (after xw: ssrc overlaps the now-dead Wc region)
    hipMemsetAsync(ws + o_cnt, 0, 32768, stream);      // cnt + cnt2
    hist_kernel<<<(nE + 255) / 256, 256, 0, stream>>>(edst, nE, cnt);
    scan_kernel<<<1, 512, 0, stream>>>(cnt, rowptr);
    scatter_kernel<<<(nE + 255) / 256, 256, 0, stream>>>(esrc, edst, nE, rowptr, cnt2, ssrc);
    lstm_kernel<<<2, 512, 0, stream>>>(xw, whh8, hidden, cell, outs, dout);
    fsfd_kernel<<<1024, 256, 0, stream>>>(outs, wsT, wdT, wso, fs, fd, fso);
    edge_csr_kernel<<<N_NODES, 64, 0, stream>>>(ssrc, rowptr, fs, fd, attn2, fso, cy, dout);
}

// Round 12
// 1659.604 us; speedup vs baseline: 3.0627x; 1.0156x over previous
//
#include <hip/hip_runtime.h>
#include <hip/hip_bf16.h>

#define N_NODES 4096
#define T_STEPS 8
#define INDIM   64
#define HDIM    128
#define G4      512                    // 4*H
#define NROWS   (N_NODES * T_STEPS)    // 32768
#define LOG2E   1.4426950408889634f

typedef __hip_bfloat16 bf16;
typedef __attribute__((ext_vector_type(8))) short bf16x8;
typedef __attribute__((ext_vector_type(4))) float f32x4;
typedef __attribute__((ext_vector_type(8))) int   i32x8;

__device__ __forceinline__ float asfloat_u(unsigned int u) {
    union { unsigned int i; float f; } v; v.i = u; return v.f;
}
// bare hardware exp2 (1 instr; OCML exp2f carries fixup code without fast-math)
__device__ __forceinline__ float fexp2(float x) {
    float r; asm("v_exp_f32 %0, %1" : "=v"(r) : "v"(x)); return r;
}

// ---------------- K0: fold weights + fp8 conversions -------------------------
// Gate pre-scaling: gates i,f,o rows scaled by -log2e, gate g rows by -2*log2e
// (device exp chains are bare v_exp_f32 = 2^x). attn2 = attn*log2e (edge exp).
#define P_O0 32768
#define P_O1 (P_O0 + 512)
#define P_O2 (P_O1 + 16384)
#define P_O3 (P_O2 + 16384)
#define P_O4 (P_O3 + 128)
#define P_O5 (P_O4 + 1)
#define P_O6 (P_O5 + 65536)
#define P_O7 (P_O6 + 128)
__global__ void prep_kernel(const float* __restrict__ pre_w, const float* __restrict__ pre_b,
                            const float* __restrict__ w_ih, const float* __restrict__ b_ih,
                            const float* __restrict__ b_hh, const float* __restrict__ w_hh,
                            const float* __restrict__ wsrc, const float* __restrict__ wdst,
                            const float* __restrict__ out_w, const float* __restrict__ out_b,
                            const float* __restrict__ gat_b, const float* __restrict__ attn,
                            float* __restrict__ Wc, float* __restrict__ bc,
                            float* __restrict__ wsT, float* __restrict__ wdT,
                            float* __restrict__ wso, float* __restrict__ cy,
                            unsigned char* __restrict__ whh8, float* __restrict__ attn2) {
    int id = blockIdx.x * 256 + threadIdx.x;
    if (id < P_O0) {
        int g = id >> 6, i = id & 63;
        float s = 0.f;
        for (int k = 0; k < HDIM; k++) s += pre_w[i * HDIM + k] * w_ih[g * HDIM + k];
        int gate = g >> 7;
        Wc[id] = s * ((gate == 2) ? -2.f * LOG2E : -LOG2E);
    } else if (id < P_O1) {
        int g = id - P_O0;
        float s = b_ih[g] + b_hh[g];
        for (int k = 0; k < HDIM; k++) s += pre_b[k] * w_ih[g * HDIM + k];
        int gate = g >> 7;
        bc[g] = s * ((gate == 2) ? -2.f * LOG2E : -LOG2E);
    } else if (id < P_O2) {
        int c = id - P_O1;
        int co = c >> 7, k = c & 127;
        wsT[c] = wsrc[k * HDIM + co];
    } else if (id < P_O3) {
        int c = id - P_O2;
        int co = c >> 7, k = c & 127;
        wdT[c] = wdst[k * HDIM + co];
    } else if (id < P_O4) {
        int hi = id - P_O3;
        float s = 0.f;
        for (int ho = 0; ho < HDIM; ho++) s += wsrc[hi * HDIM + ho] * out_w[ho];
        wso[hi] = s;
    } else if (id == P_O4) {
        float s = out_b[0];
        for (int h = 0; h < HDIM; h++) s += gat_b[h] * out_w[h];
        cy[0] = s;
    } else if (id < P_O6) {
        int c = id - P_O5;
        int gate = c >> 14;                      // row = c>>7, gate = row>>7
        float v = w_hh[c] * ((gate == 2) ? -2.f * LOG2E : -LOG2E);
        int pk = __builtin_amdgcn_cvt_pk_fp8_f32(v, v, 0, false);
        whh8[c] = (unsigned char)(pk & 0xff);
    } else if (id < P_O7) {
        int c = id - P_O6;
        attn2[c] = attn[c] * LOG2E;
    }
}

// ---------------- K1: xw[row][h*4+gate] = input[row,:64] . Wc[g,:] + bc[g] ---
__global__ __launch_bounds__(512) void xw_kernel(const float* __restrict__ input,
                                                 const float* __restrict__ Wc,
                                                 const float* __restrict__ bc,
                                                 bf16* __restrict__ xw) {
    __shared__ __align__(16) float in_lds[16 * INDIM];   // 4KB: 16 rows
    int tid = threadIdx.x;
    int rowbase = blockIdx.x * 16;
    in_lds[tid]       = input[(size_t)rowbase * INDIM + tid];
    in_lds[tid + 512] = input[(size_t)rowbase * INDIM + tid + 512];
    __syncthreads();
    int g = tid;
    int gate = g >> 7, hh = g & 127;
    float4 w[16];
    const float4* wr = reinterpret_cast<const float4*>(Wc + g * INDIM);
#pragma unroll
    for (int u = 0; u < 16; u++) w[u] = wr[u];
    float b = bc[g];
    for (int r = 0; r < 16; r++) {
        const float4* hv = reinterpret_cast<const float4*>(in_lds + r * INDIM);
        float a0 = b, a1 = 0.f, a2 = 0.f, a3 = 0.f;
#pragma unroll
        for (int u = 0; u < 16; u++) {
            float4 h4 = hv[u]; float4 wv = w[u];
            a0 = fmaf(h4.x, wv.x, a0); a1 = fmaf(h4.y, wv.y, a1);
            a2 = fmaf(h4.z, wv.z, a2); a3 = fmaf(h4.w, wv.w, a3);
        }
        xw[(size_t)(rowbase + r) * G4 + hh * 4 + gate] = __float2bfloat16((a0 + a1) + (a2 + a3));
    }
}

// ---------------- K2: LSTM scan (blocks 0,1) + CSR build (block 2) -----------
// Blocks 0,1: sequential LSTM, 4 chains each (unchanged from R9).
// Block 2: builds dst-sorted CSR (LDS hist -> scan -> LDS-atomic scatter),
// fully hidden under the 1.4 ms scan. ssrc region overlaps Wc, which is dead
// after xw_kernel (the preceding dispatch) -- legal.
__global__ __launch_bounds__(512, 1) void lstm_kernel(const bf16* __restrict__ xw,
                                                      const unsigned char* __restrict__ whh8,
                                                      const float* __restrict__ hidden0,
                                                      const float* __restrict__ cell0,
                                                      float* __restrict__ outs,
                                                      float* __restrict__ dout,
                                                      const int* __restrict__ esrc,
                                                      const int* __restrict__ edst,
                                                      int nE,
                                                      int* __restrict__ rowptr,
                                                      int* __restrict__ ssrc) {
    __shared__ __align__(16) char hbuf0[4 * 144];
    __shared__ __align__(16) char hbuf1[4 * 144];
    __shared__ int cnt[N_NODES];       // 16KB (csr block only)
    __shared__ int part[512];
    const int tid  = threadIdx.x;

    if (blockIdx.x == 2) {
        // ---- CSR build ----
        for (int i = tid; i < N_NODES; i += 512) cnt[i] = 0;
        __syncthreads();
        for (int i = tid; i < nE; i += 512) atomicAdd(&cnt[edst[i]], 1);
        __syncthreads();
        int base = tid * 8, loc[8], s = 0;
#pragma unroll
        for (int j = 0; j < 8; j++) { loc[j] = s; s += cnt[base + j]; }
        part[tid] = s;
        __syncthreads();
        for (int off = 1; off < 512; off <<= 1) {
            int v = (tid >= off) ? part[tid - off] : 0;
            __syncthreads();
            part[tid] += v;
            __syncthreads();
        }
        int pre = part[tid] - s;
#pragma unroll
        for (int j = 0; j < 8; j++) rowptr[base + j] = pre + loc[j];
        if (tid == 511) rowptr[N_NODES] = nE;
        __syncthreads();
#pragma unroll
        for (int j = 0; j < 8; j++) cnt[base + j] = pre + loc[j];
        __syncthreads();
        for (int i = tid; i < nE; i += 512) {
            int d = edst[i];
            int pos = atomicAdd(&cnt[d], 1);
            ssrc[pos] = esrc[i];
        }
        return;
    }

    // ---- LSTM scan ----
    const int w    = tid >> 6;
    const int lane = tid & 63;
    const int kg   = lane >> 4;
    const int lr   = lane & 15;
    const int q    = lr & 3;
    const int d    = lr >> 2;
    const int qg   = blockIdx.x * 4 + q;
    const int hb   = 16 * w + kg * 4 + d;

    i32x8 afr[4];
#pragma unroll
    for (int G = 0; G < 4; G++) {
        const unsigned char* rowp = whh8 + (size_t)(G * 128 + 16 * w + lr) * HDIM + kg * 32;
        afr[G] = *reinterpret_cast<const i32x8*>(rowp);
    }

    const int roff = q * 144 + kg * 32;
    const int woff = q * 144 + hb;
    const int sc   = 0x7f7f7f7f;

    float cv = cell0[qg * HDIM + hb];
    float hv = hidden0[qg * HDIM + hb];
    {
        int pk = __builtin_amdgcn_cvt_pk_fp8_f32(hv, hv, 0, false);
        *reinterpret_cast<unsigned char*>(hbuf0 + woff) = (unsigned char)(pk & 0xff);
    }

    const uint2* xq = reinterpret_cast<const uint2*>(xw) + qg * 128 + hb;
    float* outp = outs + qg * HDIM + hb;

    uint2 xb[8];
#pragma unroll
    for (int i = 0; i < 8; i++) xb[i] = xq[i * 1024];
    __syncthreads();

#define STEPX(NIDX, RB, WB, XQ)                                                      \
    do {                                                                             \
        i32x8 bfr = *reinterpret_cast<const i32x8*>(RB + roff);                      \
        f32x4 z = {0.f, 0.f, 0.f, 0.f};                                              \
        f32x4 acc0 = __builtin_amdgcn_mfma_scale_f32_16x16x128_f8f6f4(               \
            afr[0], bfr, z, 0, 0, 0, sc, 0, sc);                                     \
        f32x4 acc1 = __builtin_amdgcn_mfma_scale_f32_16x16x128_f8f6f4(               \
            afr[1], bfr, z, 0, 0, 0, sc, 0, sc);                                     \
        f32x4 acc2 = __builtin_amdgcn_mfma_scale_f32_16x16x128_f8f6f4(               \
            afr[2], bfr, z, 0, 0, 0, sc, 0, sc);                                     \
        f32x4 acc3 = __builtin_amdgcn_mfma_scale_f32_16x16x128_f8f6f4(               \
            afr[3], bfr, z, 0, 0, 0, sc, 0, sc);                                     \
        float s0 = (d & 2) ? ((d & 1) ? acc0[3] : acc0[2])                           \
                           : ((d & 1) ? acc0[1] : acc0[0]);                          \
        float s1 = (d & 2) ? ((d & 1) ? acc1[3] : acc1[2])                           \
                           : ((d & 1) ? acc1[1] : acc1[0]);                          \
        float s2 = (d & 2) ? ((d & 1) ? acc2[3] : acc2[2])                           \
                           : ((d & 1) ? acc2[1] : acc2[0]);                          \
        float s3 = (d & 2) ? ((d & 1) ? acc3[3] : acc3[2])                           \
                           : ((d & 1) ? acc3[1] : acc3[0]);                          \
        float gi = s0 + asfloat_u((XQ).x << 16);                                     \
        float gf = s1 + asfloat_u((XQ).x & 0xffff0000u);                             \
        float gg = s2 + asfloat_u((XQ).y << 16);                                     \
        float go = s3 + asfloat_u((XQ).y & 0xffff0000u);                             \
        float A = fexp2(gi), C = fexp2(gf), B = fexp2(gg);                           \
        float p = 1.f + A, r = 1.f + B, s = 1.f + C;                                 \
        float pr = p * r;                                                            \
        float num = fmaf(cv, pr, (2.f - r) * s);                                     \
        cv = num * __builtin_amdgcn_rcpf(pr * s);                                    \
        float O = fexp2(go), F = fexp2(cv * (-2.f * LOG2E));                         \
        float po = 1.f + O, rf = 1.f + F;                                            \
        hv = (2.f - rf) * __builtin_amdgcn_rcpf(po * rf);                            \
        int pk = __builtin_amdgcn_cvt_pk_fp8_f32(hv, hv, 0, false);                  \
        *reinterpret_cast<unsigned char*>(WB + woff) = (unsigned char)(pk & 0xff);   \
        outp[(NIDX) * 1024] = hv;                                                    \
        asm volatile("s_waitcnt lgkmcnt(0)" ::: "memory");                           \
        __builtin_amdgcn_s_barrier();                                                \
        __builtin_amdgcn_sched_barrier(0);                                           \
    } while (0)

    for (int n = 0; n < N_NODES; n += 8) {
#pragma unroll
        for (int i = 0; i < 8; i++) {
            if (i & 1) STEPX(n + i, hbuf1, hbuf0, xb[i]);
            else       STEPX(n + i, hbuf0, hbuf1, xb[i]);
            xb[i] = xq[(n + i + 8) * 1024];
        }
    }
#undef STEPX

    dout[NROWS + qg * HDIM + hb] = hv;                        // hT
    dout[NROWS + T_STEPS * HDIM + qg * HDIM + hb] = cv;       // cT
}

// ---------------- K3: fs/fd GEMV + fused fso ---------------------------------
__global__ __launch_bounds__(256) void fsfd_kernel(const float* __restrict__ outs,
                                                   const float* __restrict__ wsT,
                                                   const float* __restrict__ wdT,
                                                   const float* __restrict__ wso,
                                                   bf16* __restrict__ fs,
                                                   bf16* __restrict__ fd,
                                                   float* __restrict__ fso) {
    __shared__ __align__(16) float rows[32 * HDIM];    // 16KB: 32 rows
    int tid = threadIdx.x;
    size_t base = (size_t)blockIdx.x * 32 * HDIM;
#pragma unroll
    for (int j = 0; j < 16; j++) rows[tid + j * 256] = outs[base + tid + j * 256];
    __syncthreads();
    int c = tid;
    const float4* wT = reinterpret_cast<const float4*>(
        (c < HDIM) ? (wsT + c * HDIM) : (wdT + (c - HDIM) * HDIM));
    float4 w[32];
#pragma unroll
    for (int u = 0; u < 32; u++) w[u] = wT[u];
    bf16* dst = (c < HDIM) ? (fs + base + c) : (fd + base + (c - HDIM));
    for (int r = 0; r < 32; r++) {
        const float4* hv = reinterpret_cast<const float4*>(rows + r * HDIM);
        float a0 = 0.f, a1 = 0.f, a2 = 0.f, a3 = 0.f;
#pragma unroll
        for (int u = 0; u < 32; u++) {
            float4 h4 = hv[u]; float4 wv = w[u];
            a0 = fmaf(h4.x, wv.x, a0); a1 = fmaf(h4.y, wv.y, a1);
            a2 = fmaf(h4.z, wv.z, a2); a3 = fmaf(h4.w, wv.w, a3);
        }
        dst[(size_t)r * HDIM] = __float2bfloat16((a0 + a1) + (a2 + a3));
    }
    // fused fso: row-dot with wso (rotation k' = (k+tid)&127 -> conflict-free)
    if (tid < 32) {
        const float* rp = rows + tid * HDIM;
        float s = 0.f;
        for (int k = 0; k < HDIM; k++) {
            int kk = (k + tid) & 127;
            s += rp[kk] * wso[kk];
        }
        fso[blockIdx.x * 32 + tid] = s;
    }
}

// ---------------- K4: per-dst edge softmax (CSR, no atomics) -----------------
// 4 dst per block (4 waves). Lane l covers h-pair (2l, 2l+1). fd row dwords in
// registers; per source edge: vectorized fs dword loads, leaky+dot, butterfly
// reduce, a=2^v, accumulate den/num in regs. Lane 0 writes y = num/den + cy.
__global__ __launch_bounds__(256) void edge_csr_kernel(const int* __restrict__ ssrc,
                                                       const int* __restrict__ rowptr,
                                                       const bf16* __restrict__ fs,
                                                       const bf16* __restrict__ fd,
                                                       const float* __restrict__ attn2,
                                                       const float* __restrict__ fso,
                                                       const float* __restrict__ cy,
                                                       float* __restrict__ dout) {
    int dn = blockIdx.x * 4 + (threadIdx.x >> 6);
    int l  = threadIdx.x & 63;
    float a0 = attn2[2 * l], a1 = attn2[2 * l + 1];
    const unsigned int* fdp = reinterpret_cast<const unsigned int*>(fd) + (size_t)dn * 512 + l;
    unsigned int fdw[8];
#pragma unroll
    for (int t = 0; t < 8; t++) fdw[t] = fdp[t * 64];
    float den[8], num[8];
#pragma unroll
    for (int t = 0; t < 8; t++) { den[t] = 0.f; num[t] = 0.f; }
    int e0 = rowptr[dn], e1 = rowptr[dn + 1];
    for (int e = e0; e < e1; e++) {
        int s = ssrc[e];
        const unsigned int* fsp = reinterpret_cast<const unsigned int*>(fs) + (size_t)s * 512 + l;
        float4 fsoA = *reinterpret_cast<const float4*>(fso + s * 8);
        float4 fsoB = *reinterpret_cast<const float4*>(fso + s * 8 + 4);
        float fsov[8] = {fsoA.x, fsoA.y, fsoA.z, fsoA.w, fsoB.x, fsoB.y, fsoB.z, fsoB.w};
#pragma unroll
        for (int t = 0; t < 8; t++) {
            unsigned int uf = fsp[t * 64];
            float x1 = asfloat_u(uf << 16) + asfloat_u(fdw[t] << 16);
            float x2 = asfloat_u(uf & 0xffff0000u) + asfloat_u(fdw[t] & 0xffff0000u);
            x1 = fmaxf(x1, 0.f) + 0.2f * fminf(x1, 0.f);
            x2 = fmaxf(x2, 0.f) + 0.2f * fminf(x2, 0.f);
            float v = x1 * a0 + x2 * a1;
#pragma unroll
            for (int m = 32; m >= 1; m >>= 1) v += __shfl_xor(v, m, 64);
            float a = fexp2(v);
            den[t] += a;
            num[t] = fmaf(a, fsov[t], num[t]);
        }
    }
    if (l == 0) {
        float cyv = cy[0];
        float4 y0, y1;
        y0.x = num[0] * __builtin_amdgcn_rcpf(den[0]) + cyv;
        y0.y = num[1] * __builtin_amdgcn_rcpf(den[1]) + cyv;
        y0.z = num[2] * __builtin_amdgcn_rcpf(den[2]) + cyv;
        y0.w = num[3] * __builtin_amdgcn_rcpf(den[3]) + cyv;
        y1.x = num[4] * __builtin_amdgcn_rcpf(den[4]) + cyv;
        y1.y = num[5] * __builtin_amdgcn_rcpf(den[5]) + cyv;
        y1.z = num[6] * __builtin_amdgcn_rcpf(den[6]) + cyv;
        y1.w = num[7] * __builtin_amdgcn_rcpf(den[7]) + cyv;
        *reinterpret_cast<float4*>(dout + dn * 8)     = y0;
        *reinterpret_cast<float4*>(dout + dn * 8 + 4) = y1;
    }
}

extern "C" void kernel_launch(void* const* d_in, const int* in_sizes, int n_in,
                              void* d_out, int out_size, void* d_ws, size_t ws_size,
                              hipStream_t stream) {
    const float* input  = (const float*)d_in[0];
    const float* hidden = (const float*)d_in[1];
    const float* cell   = (const float*)d_in[2];
    const float* pre_w  = (const float*)d_in[3];
    const float* pre_b  = (const float*)d_in[4];
    const float* w_ih   = (const float*)d_in[5];
    const float* w_hh   = (const float*)d_in[6];
    const float* b_ih   = (const float*)d_in[7];
    const float* b_hh   = (const float*)d_in[8];
    const float* wsrc   = (const float*)d_in[9];
    const float* wdst   = (const float*)d_in[10];
    const float* attn   = (const float*)d_in[11];
    const float* gatb   = (const float*)d_in[12];
    const float* outw   = (const float*)d_in[13];
    const float* outb   = (const float*)d_in[14];
    const int*   esrc   = (const int*)d_in[15];
    const int*   edst   = (const int*)d_in[16];
    int nE = in_sizes[15];
    float* dout = (float*)d_out;
    char* ws = (char*)d_ws;

    // workspace layout (bytes, 256-aligned)
    const size_t o_xw    = 0;                 // 32768*512*2  = 33,554,432
    const size_t o_outs  = 33554432;          // 32768*128*4  = 16,777,216
    const size_t o_fs    = 50331648;          //  8,388,608
    const size_t o_fd    = 58720256;          //  8,388,608
    const size_t o_fso   = 67108864;          //    131,072
    const size_t o_rowptr= 67272704;          //     16,640
    const size_t o_ssrc  = 67289344;          //    278,528 -> ends 67,567,872
                                              //    (overlaps Wc/bc: dead after xw;
                                              //     written by lstm-dispatch block 2)
    const size_t o_wc    = 67502080;          //    131,072  (dead after xw_kernel)
    const size_t o_bc    = 67633152;          //      2,048
    const size_t o_wsT   = 67635200;          //     65,536
    const size_t o_wdT   = 67700736;          //     65,536
    const size_t o_wso   = 67766272;          //        512
    const size_t o_cy    = 67766784;          //        256 (4 used)
    const size_t o_attn2 = 67767040;          //        512
    const size_t o_whh8  = o_fs;              // fp8 w_hh overlaps fs (disjoint in time)

    bf16*  xw    = (bf16*)(ws + o_xw);
    float* outs  = (float*)(ws + o_outs);
    bf16*  fs    = (bf16*)(ws + o_fs);
    bf16*  fd    = (bf16*)(ws + o_fd);
    float* fso   = (float*)(ws + o_fso);
    int*   rowptr= (int*)(ws + o_rowptr);
    int*   ssrc  = (int*)(ws + o_ssrc);
    float* Wc    = (float*)(ws + o_wc);
    float* bc    = (float*)(ws + o_bc);
    float* wsT   = (float*)(ws + o_wsT);
    float* wdT   = (float*)(ws + o_wdT);
    float* wso   = (float*)(ws + o_wso);
    float* cy    = (float*)(ws + o_cy);
    float* attn2 = (float*)(ws + o_attn2);
    unsigned char* whh8 = (unsigned char*)(ws + o_whh8);

    prep_kernel<<<516, 256, 0, stream>>>(pre_w, pre_b, w_ih, b_ih, b_hh, w_hh, wsrc, wdst,
                                         outw, outb, gatb, attn,
                                         Wc, bc, wsT, wdT, wso, cy, whh8, attn2);
    xw_kernel<<<2048, 512, 0, stream>>>(input, Wc, bc, xw);
    lstm_kernel<<<3, 512, 0, stream>>>(xw, whh8, hidden, cell, outs, dout,
                                       esrc, edst, nE, rowptr, ssrc);
    fsfd_kernel<<<1024, 256, 0, stream>>>(outs, wsT, wdT, wso, fs, fd, fso);
    edge_csr_kernel<<<N_NODES / 4, 256, 0, stream>>>(ssrc, rowptr, fs, fd, attn2, fso, cy, dout);
}

// Round 14
// 1650.472 us; speedup vs baseline: 3.0797x; 1.0055x over previous
//
#include <hip/hip_runtime.h>
#include <hip/hip_bf16.h>

#define N_NODES 4096
#define T_STEPS 8
#define INDIM   64
#define HDIM    128
#define G4      512                    // 4*H
#define NROWS   (N_NODES * T_STEPS)    // 32768
#define LOG2E   1.4426950408889634f

typedef __hip_bfloat16 bf16;
typedef __attribute__((ext_vector_type(8))) short bf16x8;
typedef __attribute__((ext_vector_type(4))) float f32x4;
typedef __attribute__((ext_vector_type(8))) int   i32x8;

__device__ __forceinline__ float asfloat_u(unsigned int u) {
    union { unsigned int i; float f; } v; v.i = u; return v.f;
}
// bare hardware exp2 (1 instr; OCML exp2f carries fixup code without fast-math)
__device__ __forceinline__ float fexp2(float x) {
    float r; asm("v_exp_f32 %0, %1" : "=v"(r) : "v"(x)); return r;
}

// ---------------- K0: fold weights + fp8 conversions -------------------------
// Gate pre-scaling: gates i,f,o rows scaled by -log2e, gate g rows by -2*log2e
// (device exp chains are bare v_exp_f32 = 2^x). attn2 = attn*log2e (edge exp).
#define P_O0 32768
#define P_O1 (P_O0 + 512)
#define P_O2 (P_O1 + 16384)
#define P_O3 (P_O2 + 16384)
#define P_O4 (P_O3 + 128)
#define P_O5 (P_O4 + 1)
#define P_O6 (P_O5 + 65536)
#define P_O7 (P_O6 + 128)
__global__ void prep_kernel(const float* __restrict__ pre_w, const float* __restrict__ pre_b,
                            const float* __restrict__ w_ih, const float* __restrict__ b_ih,
                            const float* __restrict__ b_hh, const float* __restrict__ w_hh,
                            const float* __restrict__ wsrc, const float* __restrict__ wdst,
                            const float* __restrict__ out_w, const float* __restrict__ out_b,
                            const float* __restrict__ gat_b, const float* __restrict__ attn,
                            float* __restrict__ Wc, float* __restrict__ bc,
                            float* __restrict__ wsT, float* __restrict__ wdT,
                            float* __restrict__ wso, float* __restrict__ cy,
                            unsigned char* __restrict__ whh8, float* __restrict__ attn2) {
    int id = blockIdx.x * 256 + threadIdx.x;
    if (id < P_O0) {
        int g = id >> 6, i = id & 63;
        float s = 0.f;
        for (int k = 0; k < HDIM; k++) s += pre_w[i * HDIM + k] * w_ih[g * HDIM + k];
        int gate = g >> 7;
        Wc[id] = s * ((gate == 2) ? -2.f * LOG2E : -LOG2E);
    } else if (id < P_O1) {
        int g = id - P_O0;
        float s = b_ih[g] + b_hh[g];
        for (int k = 0; k < HDIM; k++) s += pre_b[k] * w_ih[g * HDIM + k];
        int gate = g >> 7;
        bc[g] = s * ((gate == 2) ? -2.f * LOG2E : -LOG2E);
    } else if (id < P_O2) {
        int c = id - P_O1;
        int co = c >> 7, k = c & 127;
        wsT[c] = wsrc[k * HDIM + co];
    } else if (id < P_O3) {
        int c = id - P_O2;
        int co = c >> 7, k = c & 127;
        wdT[c] = wdst[k * HDIM + co];
    } else if (id < P_O4) {
        int hi = id - P_O3;
        float s = 0.f;
        for (int ho = 0; ho < HDIM; ho++) s += wsrc[hi * HDIM + ho] * out_w[ho];
        wso[hi] = s;
    } else if (id == P_O4) {
        float s = out_b[0];
        for (int h = 0; h < HDIM; h++) s += gat_b[h] * out_w[h];
        cy[0] = s;
    } else if (id < P_O6) {
        int c = id - P_O5;
        int gate = c >> 14;                      // row = c>>7, gate = row>>7
        float v = w_hh[c] * ((gate == 2) ? -2.f * LOG2E : -LOG2E);
        int pk = __builtin_amdgcn_cvt_pk_fp8_f32(v, v, 0, false);
        whh8[c] = (unsigned char)(pk & 0xff);
    } else if (id < P_O7) {
        int c = id - P_O6;
        attn2[c] = attn[c] * LOG2E;
    }
}

// ---------------- K1: xw[row][h*4+gate] = input[row,:64] . Wc[g,:] + bc[g] ---
__global__ __launch_bounds__(512) void xw_kernel(const float* __restrict__ input,
                                                 const float* __restrict__ Wc,
                                                 const float* __restrict__ bc,
                                                 bf16* __restrict__ xw) {
    __shared__ __align__(16) float in_lds[16 * INDIM];   // 4KB: 16 rows
    int tid = threadIdx.x;
    int rowbase = blockIdx.x * 16;
    in_lds[tid]       = input[(size_t)rowbase * INDIM + tid];
    in_lds[tid + 512] = input[(size_t)rowbase * INDIM + tid + 512];
    __syncthreads();
    int g = tid;
    int gate = g >> 7, hh = g & 127;
    float4 w[16];
    const float4* wr = reinterpret_cast<const float4*>(Wc + g * INDIM);
#pragma unroll
    for (int u = 0; u < 16; u++) w[u] = wr[u];
    float b = bc[g];
    for (int r = 0; r < 16; r++) {
        const float4* hv = reinterpret_cast<const float4*>(in_lds + r * INDIM);
        float a0 = b, a1 = 0.f, a2 = 0.f, a3 = 0.f;
#pragma unroll
        for (int u = 0; u < 16; u++) {
            float4 h4 = hv[u]; float4 wv = w[u];
            a0 = fmaf(h4.x, wv.x, a0); a1 = fmaf(h4.y, wv.y, a1);
            a2 = fmaf(h4.z, wv.z, a2); a3 = fmaf(h4.w, wv.w, a3);
        }
        xw[(size_t)(rowbase + r) * G4 + hh * 4 + gate] = __float2bfloat16((a0 + a1) + (a2 + a3));
    }
}

// ---------------- K2: LSTM scan (blocks 0-3) + CSR build (block 4) -----------
// LSTM: 4 blocks x 2 chains, 256 threads (4 waves) => 1 wave/SIMD, no issue
// contention. Wave w covers h rows [32w,32w+32) via 8 A-tiles (G x rowblock b).
// Lane (kg,lr): q=lr&1 (chain), d=(lr>>1)&3 (C reg), b=lr>>3 (tile half)
// -> unique (h,chain) per lane, 1 h of gate math each (zero duplication).
// Block 4: dst-sorted CSR build (LDS hist/scan/scatter), hidden under the scan.
__global__ __launch_bounds__(256, 1) void lstm_kernel(const bf16* __restrict__ xw,
                                                      const unsigned char* __restrict__ whh8,
                                                      const float* __restrict__ hidden0,
                                                      const float* __restrict__ cell0,
                                                      float* __restrict__ outs,
                                                      float* __restrict__ dout,
                                                      const int* __restrict__ esrc,
                                                      const int* __restrict__ edst,
                                                      int nE,
                                                      int* __restrict__ rowptr,
                                                      int* __restrict__ ssrc) {
    __shared__ __align__(16) char hbuf0[2 * 144];
    __shared__ __align__(16) char hbuf1[2 * 144];
    __shared__ int cnt[N_NODES];       // 16KB (csr block only)
    __shared__ int part[256];
    const int tid  = threadIdx.x;

    if (blockIdx.x == 4) {
        // ---- CSR build (256 threads) ----
        for (int i = tid; i < N_NODES; i += 256) cnt[i] = 0;
        __syncthreads();
        for (int i = tid; i < nE; i += 256) atomicAdd(&cnt[edst[i]], 1);
        __syncthreads();
        int base = tid * 16, loc[16], s = 0;
#pragma unroll
        for (int j = 0; j < 16; j++) { loc[j] = s; s += cnt[base + j]; }
        part[tid] = s;
        __syncthreads();
        for (int off = 1; off < 256; off <<= 1) {
            int v = (tid >= off) ? part[tid - off] : 0;
            __syncthreads();
            part[tid] += v;
            __syncthreads();
        }
        int pre = part[tid] - s;
#pragma unroll
        for (int j = 0; j < 16; j++) rowptr[base + j] = pre + loc[j];
        if (tid == 255) rowptr[N_NODES] = nE;
        __syncthreads();
#pragma unroll
        for (int j = 0; j < 16; j++) cnt[base + j] = pre + loc[j];
        __syncthreads();
        for (int i = tid; i < nE; i += 256) {
            int d = edst[i];
            int pos = atomicAdd(&cnt[d], 1);
            ssrc[pos] = esrc[i];
        }
        return;
    }

    // ---- LSTM scan ----
    const int w    = tid >> 6;         // wave 0..3
    const int lane = tid & 63;
    const int kg   = lane >> 4;        // 0..3 (k-group of 32; C row block)
    const int lr   = lane & 15;        // A row in tile; C col
    const int q    = lr & 1;           // chain within block
    const int d    = (lr >> 1) & 3;    // which C reg this lane consumes
    const int b    = lr >> 3;          // which row-block tile
    const int qg   = blockIdx.x * 2 + q;              // global chain (t)
    const int hb   = 32 * w + 16 * b + kg * 4 + d;    // this lane's h index

    // Persistent A fragments: tile (G, bb) rows G*128 + 32w + 16bb + lr
    i32x8 afr[4][2];
#pragma unroll
    for (int G = 0; G < 4; G++)
#pragma unroll
        for (int bb = 0; bb < 2; bb++) {
            const unsigned char* rowp =
                whh8 + (size_t)(G * 128 + 32 * w + 16 * bb + lr) * HDIM + kg * 32;
            afr[G][bb] = *reinterpret_cast<const i32x8*>(rowp);
        }

    const int roff = q * 144 + kg * 32;   // B-frag read base (32 contiguous bytes)
    const int woff = q * 144 + hb;        // h write (1 byte)
    const int sc   = 0x7f7f7f7f;          // e8m0 scale 1.0 in every byte

    float cv = cell0[qg * HDIM + hb];
    float hv = hidden0[qg * HDIM + hb];
    {
        int pk = __builtin_amdgcn_cvt_pk_fp8_f32(hv, hv, 0, false);
        *reinterpret_cast<unsigned char*>(hbuf0 + woff) = (unsigned char)(pk & 0xff);
    }

    // xw: row (n*8+qg), this h's 4 gates = 8 bytes -> uint2 idx row*128 + hb
    const uint2* xq = reinterpret_cast<const uint2*>(xw) + qg * 128 + hb;
    float* outp = outs + qg * HDIM + hb;

    uint2 xb[8];
#pragma unroll
    for (int i = 0; i < 8; i++) xb[i] = xq[i * 1024];
    __syncthreads();

#define SEL(M) ((d & 2) ? ((d & 1) ? (M)[3] : (M)[2]) : ((d & 1) ? (M)[1] : (M)[0]))
#define STEPX(NIDX, RB, WB, XQ)                                                      \
    do {                                                                             \
        i32x8 bfr = *reinterpret_cast<const i32x8*>(RB + roff);                      \
        f32x4 z = {0.f, 0.f, 0.f, 0.f};                                              \
        f32x4 a00 = __builtin_amdgcn_mfma_scale_f32_16x16x128_f8f6f4(                \
            afr[0][0], bfr, z, 0, 0, 0, sc, 0, sc);                                  \
        f32x4 a01 = __builtin_amdgcn_mfma_scale_f32_16x16x128_f8f6f4(                \
            afr[0][1], bfr, z, 0, 0, 0, sc, 0, sc);                                  \
        f32x4 a10 = __builtin_amdgcn_mfma_scale_f32_16x16x128_f8f6f4(                \
            afr[1][0], bfr, z, 0, 0, 0, sc, 0, sc);                                  \
        f32x4 a11 = __builtin_amdgcn_mfma_scale_f32_16x16x128_f8f6f4(                \
            afr[1][1], bfr, z, 0, 0, 0, sc, 0, sc);                                  \
        f32x4 a20 = __builtin_amdgcn_mfma_scale_f32_16x16x128_f8f6f4(                \
            afr[2][0], bfr, z, 0, 0, 0, sc, 0, sc);                                  \
        f32x4 a21 = __builtin_amdgcn_mfma_scale_f32_16x16x128_f8f6f4(                \
            afr[2][1], bfr, z, 0, 0, 0, sc, 0, sc);                                  \
        f32x4 a30 = __builtin_amdgcn_mfma_scale_f32_16x16x128_f8f6f4(                \
            afr[3][0], bfr, z, 0, 0, 0, sc, 0, sc);                                  \
        f32x4 a31 = __builtin_amdgcn_mfma_scale_f32_16x16x128_f8f6f4(                \
            afr[3][1], bfr, z, 0, 0, 0, sc, 0, sc);                                  \
        f32x4 m0 = b ? a01 : a00;                                                    \
        f32x4 m1 = b ? a11 : a10;                                                    \
        f32x4 m2 = b ? a21 : a20;                                                    \
        f32x4 m3 = b ? a31 : a30;                                                    \
        float gi = SEL(m0) + asfloat_u((XQ).x << 16);                                \
        float gf = SEL(m1) + asfloat_u((XQ).x & 0xffff0000u);                        \
        float gg = SEL(m2) + asfloat_u((XQ).y << 16);                                \
        float go = SEL(m3) + asfloat_u((XQ).y & 0xffff0000u);                        \
        float A = fexp2(gi), C = fexp2(gf), B = fexp2(gg);                           \
        float p = 1.f + A, r = 1.f + B, s = 1.f + C;                                 \
        float pr = p * r;                                                            \
        float num = fmaf(cv, pr, (2.f - r) * s);                                     \
        cv = num * __builtin_amdgcn_rcpf(pr * s);                                    \
        float O = fexp2(go), F = fexp2(cv * (-2.f * LOG2E));                         \
        float po = 1.f + O, rf = 1.f + F;                                            \
        hv = (2.f - rf) * __builtin_amdgcn_rcpf(po * rf);                            \
        int pk = __builtin_amdgcn_cvt_pk_fp8_f32(hv, hv, 0, false);                  \
        *reinterpret_cast<unsigned char*>(WB + woff) = (unsigned char)(pk & 0xff);   \
        outp[(NIDX) * 1024] = hv;                                                    \
        asm volatile("s_waitcnt lgkmcnt(0)" ::: "memory");                           \
        __builtin_amdgcn_s_barrier();                                                \
        __builtin_amdgcn_sched_barrier(0);                                           \
    } while (0)

    for (int n = 0; n < N_NODES; n += 8) {
#pragma unroll
        for (int i = 0; i < 8; i++) {
            if (i & 1) STEPX(n + i, hbuf1, hbuf0, xb[i]);
            else       STEPX(n + i, hbuf0, hbuf1, xb[i]);
            // reload 8 steps ahead; tail reads land in outs region (in-bounds,
            // never consumed) so no conditionals needed
            xb[i] = xq[(n + i + 8) * 1024];
        }
    }
#undef STEPX
#undef SEL

    dout[NROWS + qg * HDIM + hb] = hv;                        // hT
    dout[NROWS + T_STEPS * HDIM + qg * HDIM + hb] = cv;       // cT
}

// ---------------- K3: fs/fd GEMV + fused fso ---------------------------------
__global__ __launch_bounds__(256) void fsfd_kernel(const float* __restrict__ outs,
                                                   const float* __restrict__ wsT,
                                                   const float* __restrict__ wdT,
                                                   const float* __restrict__ wso,
                                                   bf16* __restrict__ fs,
                                                   bf16* __restrict__ fd,
                                                   float* __restrict__ fso) {
    __shared__ __align__(16) float rows[32 * HDIM];    // 16KB: 32 rows
    int tid = threadIdx.x;
    size_t base = (size_t)blockIdx.x * 32 * HDIM;
#pragma unroll
    for (int j = 0; j < 16; j++) rows[tid + j * 256] = outs[base + tid + j * 256];
    __syncthreads();
    int c = tid;
    const float4* wT = reinterpret_cast<const float4*>(
        (c < HDIM) ? (wsT + c * HDIM) : (wdT + (c - HDIM) * HDIM));
    float4 w[32];
#pragma unroll
    for (int u = 0; u < 32; u++) w[u] = wT[u];
    bf16* dst = (c < HDIM) ? (fs + base + c) : (fd + base + (c - HDIM));
    for (int r = 0; r < 32; r++) {
        const float4* hv = reinterpret_cast<const float4*>(rows + r * HDIM);
        float a0 = 0.f, a1 = 0.f, a2 = 0.f, a3 = 0.f;
#pragma unroll
        for (int u = 0; u < 32; u++) {
            float4 h4 = hv[u]; float4 wv = w[u];
            a0 = fmaf(h4.x, wv.x, a0); a1 = fmaf(h4.y, wv.y, a1);
            a2 = fmaf(h4.z, wv.z, a2); a3 = fmaf(h4.w, wv.w, a3);
        }
        dst[(size_t)r * HDIM] = __float2bfloat16((a0 + a1) + (a2 + a3));
    }
    // fused fso: row-dot with wso (rotation k' = (k+tid)&127 -> conflict-free)
    if (tid < 32) {
        const float* rp = rows + tid * HDIM;
        float s = 0.f;
        for (int k = 0; k < HDIM; k++) {
            int kk = (k + tid) & 127;
            s += rp[kk] * wso[kk];
        }
        fso[blockIdx.x * 32 + tid] = s;
    }
}

// ---------------- K4: per-dst edge softmax (CSR, no atomics) -----------------
// 4 dst per block (4 waves). Lane l covers h-pair (2l, 2l+1). fd row dwords in
// registers; per source edge: vectorized fs dword loads, leaky+dot, butterfly
// reduce, a=2^v, accumulate den/num in regs. Lane 0 writes y = num/den + cy.
__global__ __launch_bounds__(256) void edge_csr_kernel(const int* __restrict__ ssrc,
                                                       const int* __restrict__ rowptr,
                                                       const bf16* __restrict__ fs,
                                                       const bf16* __restrict__ fd,
                                                       const float* __restrict__ attn2,
                                                       const float* __restrict__ fso,
                                                       const float* __restrict__ cy,
                                                       float* __restrict__ dout) {
    int dn = blockIdx.x * 4 + (threadIdx.x >> 6);
    int l  = threadIdx.x & 63;
    float a0 = attn2[2 * l], a1 = attn2[2 * l + 1];
    const unsigned int* fdp = reinterpret_cast<const unsigned int*>(fd) + (size_t)dn * 512 + l;
    unsigned int fdw[8];
#pragma unroll
    for (int t = 0; t < 8; t++) fdw[t] = fdp[t * 64];
    float den[8], num[8];
#pragma unroll
    for (int t = 0; t < 8; t++) { den[t] = 0.f; num[t] = 0.f; }
    int e0 = rowptr[dn], e1 = rowptr[dn + 1];
    for (int e = e0; e < e1; e++) {
        int s = ssrc[e];
        const unsigned int* fsp = reinterpret_cast<const unsigned int*>(fs) + (size_t)s * 512 + l;
        float4 fsoA = *reinterpret_cast<const float4*>(fso + s * 8);
        float4 fsoB = *reinterpret_cast<const float4*>(fso + s * 8 + 4);
        float fsov[8] = {fsoA.x, fsoA.y, fsoA.z, fsoA.w, fsoB.x, fsoB.y, fsoB.z, fsoB.w};
#pragma unroll
        for (int t = 0; t < 8; t++) {
            unsigned int uf = fsp[t * 64];
            float x1 = asfloat_u(uf << 16) + asfloat_u(fdw[t] << 16);
            float x2 = asfloat_u(uf & 0xffff0000u) + asfloat_u(fdw[t] & 0xffff0000u);
            x1 = fmaxf(x1, 0.f) + 0.2f * fminf(x1, 0.f);
            x2 = fmaxf(x2, 0.f) + 0.2f * fminf(x2, 0.f);
            float v = x1 * a0 + x2 * a1;
#pragma unroll
            for (int m = 32; m >= 1; m >>= 1) v += __shfl_xor(v, m, 64);
            float a = fexp2(v);
            den[t] += a;
            num[t] = fmaf(a, fsov[t], num[t]);
        }
    }
    if (l == 0) {
        float cyv = cy[0];
        float4 y0, y1;
        y0.x = num[0] * __builtin_amdgcn_rcpf(den[0]) + cyv;
        y0.y = num[1] * __builtin_amdgcn_rcpf(den[1]) + cyv;
        y0.z = num[2] * __builtin_amdgcn_rcpf(den[2]) + cyv;
        y0.w = num[3] * __builtin_amdgcn_rcpf(den[3]) + cyv;
        y1.x = num[4] * __builtin_amdgcn_rcpf(den[4]) + cyv;
        y1.y = num[5] * __builtin_amdgcn_rcpf(den[5]) + cyv;
        y1.z = num[6] * __builtin_amdgcn_rcpf(den[6]) + cyv;
        y1.w = num[7] * __builtin_amdgcn_rcpf(den[7]) + cyv;
        *reinterpret_cast<float4*>(dout + dn * 8)     = y0;
        *reinterpret_cast<float4*>(dout + dn * 8 + 4) = y1;
    }
}

extern "C" void kernel_launch(void* const* d_in, const int* in_sizes, int n_in,
                              void* d_out, int out_size, void* d_ws, size_t ws_size,
                              hipStream_t stream) {
    const float* input  = (const float*)d_in[0];
    const float* hidden = (const float*)d_in[1];
    const float* cell   = (const float*)d_in[2];
    const float* pre_w  = (const float*)d_in[3];
    const float* pre_b  = (const float*)d_in[4];
    const float* w_ih   = (const float*)d_in[5];
    const float* w_hh   = (const float*)d_in[6];
    const float* b_ih   = (const float*)d_in[7];
    const float* b_hh   = (const float*)d_in[8];
    const float* wsrc   = (const float*)d_in[9];
    const float* wdst   = (const float*)d_in[10];
    const float* attn   = (const float*)d_in[11];
    const float* gatb   = (const float*)d_in[12];
    const float* outw   = (const float*)d_in[13];
    const float* outb   = (const float*)d_in[14];
    const int*   esrc   = (const int*)d_in[15];
    const int*   edst   = (const int*)d_in[16];
    int nE = in_sizes[15];
    float* dout = (float*)d_out;
    char* ws = (char*)d_ws;

    // workspace layout (bytes, 256-aligned)
    const size_t o_xw    = 0;                 // 32768*512*2  = 33,554,432
    const size_t o_outs  = 33554432;          // 32768*128*4  = 16,777,216
    const size_t o_fs    = 50331648;          //  8,388,608
    const size_t o_fd    = 58720256;          //  8,388,608
    const size_t o_fso   = 67108864;          //    131,072
    const size_t o_rowptr= 67272704;          //     16,640
    const size_t o_ssrc  = 67289344;          //    278,528 -> ends 67,567,872
                                              //    (overlaps Wc/bc: dead after xw;
                                              //     written by lstm-dispatch block 4)
    const size_t o_wc    = 67502080;          //    131,072  (dead after xw_kernel)
    const size_t o_bc    = 67633152;          //      2,048
    const size_t o_wsT   = 67635200;          //     65,536
    const size_t o_wdT   = 67700736;          //     65,536
    const size_t o_wso   = 67766272;          //        512
    const size_t o_cy    = 67766784;          //        256 (4 used)
    const size_t o_attn2 = 67767040;          //        512
    const size_t o_whh8  = o_fs;              // fp8 w_hh overlaps fs (disjoint in time)

    bf16*  xw    = (bf16*)(ws + o_xw);
    float* outs  = (float*)(ws + o_outs);
    bf16*  fs    = (bf16*)(ws + o_fs);
    bf16*  fd    = (bf16*)(ws + o_fd);
    float* fso   = (float*)(ws + o_fso);
    int*   rowptr= (int*)(ws + o_rowptr);
    int*   ssrc  = (int*)(ws + o_ssrc);
    float* Wc    = (float*)(ws + o_wc);
    float* bc    = (float*)(ws + o_bc);
    float* wsT   = (float*)(ws + o_wsT);
    float* wdT   = (float*)(ws + o_wdT);
    float* wso   = (float*)(ws + o_wso);
    float* cy    = (float*)(ws + o_cy);
    float* attn2 = (float*)(ws + o_attn2);
    unsigned char* whh8 = (unsigned char*)(ws + o_whh8);

    prep_kernel<<<516, 256, 0, stream>>>(pre_w, pre_b, w_ih, b_ih, b_hh, w_hh, wsrc, wdst,
                                         outw, outb, gatb, attn,
                                         Wc, bc, wsT, wdT, wso, cy, whh8, attn2);
    xw_kernel<<<2048, 512, 0, stream>>>(input, Wc, bc, xw);
    lstm_kernel<<<5, 256, 0, stream>>>(xw, whh8, hidden, cell, outs, dout,
                                       esrc, edst, nE, rowptr, ssrc);
    fsfd_kernel<<<1024, 256, 0, stream>>>(outs, wsT, wdT, wso, fs, fd, fso);
    edge_csr_kernel<<<N_NODES / 4, 256, 0, stream>>>(ssrc, rowptr, fs, fd, attn2, fso, cy, dout);
}